// Round 4
// baseline (397.762 us; speedup 1.0000x reference)
//
#include <hip/hip_runtime.h>
#include <math.h>

#define SCALE_ 0.08838834764831843f

typedef __attribute__((ext_vector_type(8))) short bf16x8;
typedef __attribute__((ext_vector_type(4))) float f32x4;
typedef __attribute__((ext_vector_type(8))) unsigned short u16x8;

// ---- workspace layout (float offsets), total ~2.4M floats = 9.6 MB ----
static const size_t OFF_VAR   = 0;        // 32768
static const size_t OFF_DENOM = 32768;    // 64
static const size_t OFF_GSUM  = 32832;    // 256
static const size_t OFF_BIAS  = 33088;    // 256
static const size_t OFF_QKB   = 33344;    // 128
static const size_t OFF_SSUM  = 33472;    // 128
static const size_t OFF_SLOTS = 33600;    // 16384
static const size_t OFF_Q     = 49984;    // 16384
static const size_t OFF_U     = 66368;    // 16384
static const size_t OFF_WQBF  = 82752;    // 8192 fl (16384 bf16) Wq[128][128]
static const size_t OFF_WIHBF = 90944;    // 24576 fl Wih[384][128]
static const size_t OFF_WHHBF = 115520;   // 24576 fl Whh[384][128]
static const size_t OFF_W1BF  = 140096;   // 32768 fl W1[512][128]
static const size_t OFF_WM2BF = 172864;   // 32768 fl W2[128][512]
static const size_t OFF_WKVBF = 205632;   // 98304 fl (196608 bf16) [256][768] SWIZZLED
static const size_t OFF_KVB   = 303936;   // 2097152 fl (4194304 bf16) [b][n][256]

__device__ __forceinline__ float wred64(float v) {
#pragma unroll
  for (int off = 32; off > 0; off >>= 1) v += __shfl_xor(v, off, 64);
  return v;
}

__device__ __forceinline__ unsigned short f2bf(float f) {
  unsigned u = __float_as_uint(f);
  unsigned r = (u + 0x7fffu + ((u >> 16) & 1u)) >> 16;
  return (unsigned short)r;
}

__device__ __forceinline__ unsigned pack2(float a, float b) {
  return (unsigned)f2bf(a) | ((unsigned)f2bf(b) << 16);
}

__device__ __forceinline__ float bf2f(unsigned short s) {
  return __uint_as_float((unsigned)s << 16);
}

// ---- 1. merged prep: wkv (swizzled bf16), gsum/bias, bf16 weight copies, denom
__global__ __launch_bounds__(256) void prep_all_k(
    const float* __restrict__ Wk, const float* __restrict__ Wv,
    const float* __restrict__ g, const float* __restrict__ bb,
    const float* __restrict__ Wq, const float* __restrict__ Wih,
    const float* __restrict__ Whh, const float* __restrict__ W1,
    const float* __restrict__ W2, const float* __restrict__ pm,
    unsigned short* __restrict__ wkv, float* __restrict__ gsum,
    float* __restrict__ biasArr,
    unsigned short* __restrict__ Wqbf, unsigned short* __restrict__ Wihbf,
    unsigned short* __restrict__ Whhbf, unsigned short* __restrict__ W1bf,
    unsigned short* __restrict__ Wm2bf, float* __restrict__ denomArr)
{
  __shared__ float red4[4];
  int bi = blockIdx.x, t = threadIdx.x;
  if (bi < 64) {
    // fold LN gain into Wk/Wv, bf16, XOR-swizzle groups of 8 within 64-chunks
    int j = bi*4 + (t >> 6), lane = t & 63;
    const float* w = (j < 128) ? (Wk + (size_t)j*768) : (Wv + (size_t)(j-128)*768);
    float gs = 0.f, bs = 0.f;
    int key = j & 7;
#pragma unroll
    for (int s = 0; s < 12; ++s) {
      int dd = lane + s*64;
      float wv = w[dd], gv = g[dd];
      gs += gv*wv; bs += bb[dd]*wv;
      int sw = (dd & ~63) | (((((dd >> 3) & 7) ^ key)) << 3) | (dd & 7);
      wkv[(size_t)j*768 + sw] = f2bf(wv*gv);
    }
    gs = wred64(gs); bs = wred64(bs);
    if (lane == 0) { gsum[j] = gs; biasArr[j] = bs; }
  } else if (bi < 128) {
    int idx = (bi-64)*256 + t;  Wqbf[idx]  = f2bf(Wq[idx]);
  } else if (bi < 320) {
    int idx = (bi-128)*256 + t; Wihbf[idx] = f2bf(Wih[idx]);
  } else if (bi < 512) {
    int idx = (bi-320)*256 + t; Whhbf[idx] = f2bf(Whh[idx]);
  } else if (bi < 768) {
    int idx = (bi-512)*256 + t; W1bf[idx]  = f2bf(W1[idx]);
  } else if (bi < 1024) {
    int idx = (bi-768)*256 + t; Wm2bf[idx] = f2bf(W2[idx]);
  } else {
    int bk = bi - 1024;
    float s = 0.f;
#pragma unroll
    for (int k = 0; k < 16; ++k) s += pm[bk*4096 + t + k*256];
    s = wred64(s);
    if ((t & 63) == 0) red4[t >> 6] = s;
    __syncthreads();
    if (t == 0) denomArr[bk] = (red4[0]+red4[1]+red4[2]+red4[3])*(1.f/4096.f);
  }
}

// ---- 2. MFMA GEMM: tokens[32768,768] -> KVb bf16 [b][n][256] (+ var) ----
// grid 512: block = 64 rows x 256 cols. Swizzled LDS (conflict-free frag reads).
__global__ __launch_bounds__(256) void gemm_kv_k(
    const float* __restrict__ tokens, const unsigned short* __restrict__ wkv,
    const float* __restrict__ gsum, unsigned short* __restrict__ KVb,
    float* __restrict__ varArr)
{
  __shared__ unsigned short As[64*64];   // swizzled
  __shared__ unsigned short Bs[256*64];  // swizzled via pre-swizzled wkv
  __shared__ float meanS[64];
  int r0 = blockIdx.x*64;
  int t = threadIdx.x;
  int w = t >> 6, lane = t & 63;
  int lm = lane & 15, lq = lane >> 4;
  int g16 = t >> 4, seg = t & 15;
  int m0 = (w >> 1)*32, n0 = (w & 1)*128;

  f32x4 acc[2][8];
#pragma unroll
  for (int a = 0; a < 2; ++a)
#pragma unroll
    for (int c = 0; c < 8; ++c) acc[a][c] = f32x4{0.f, 0.f, 0.f, 0.f};
  float s1[4] = {0.f,0.f,0.f,0.f}, s2[4] = {0.f,0.f,0.f,0.f};

  for (int k0 = 0; k0 < 768; k0 += 64) {
    __syncthreads();
#pragma unroll
    for (int s = 0; s < 8; ++s) {
      int row = w*64 + s*8;
      __builtin_amdgcn_global_load_lds(
        (const __attribute__((address_space(1))) void*)
          (wkv + (size_t)(row + (lane >> 3))*768 + k0 + (lane & 7)*8),
        (__attribute__((address_space(3))) void*)(&Bs[row*64]), 16, 0, 0);
    }
#pragma unroll
    for (int p = 0; p < 4; ++p) {
      int row = p*16 + g16;
      float4 x = *(const float4*)(tokens + (size_t)(r0 + row)*768 + k0 + seg*4);
      s1[p] += x.x + x.y + x.z + x.w;
      s2[p] += x.x*x.x + x.y*x.y + x.z*x.z + x.w*x.w;
      int off = row*64 + (((seg >> 1) ^ (row & 7)) << 3) + (seg & 1)*4;
      *(uint2*)(&As[off]) = make_uint2(pack2(x.x, x.y), pack2(x.z, x.w));
    }
    __syncthreads();
#pragma unroll
    for (int kk8 = 0; kk8 < 8; kk8 += 4) {
      bf16x8 af[2], bfr[8];
#pragma unroll
      for (int mt = 0; mt < 2; ++mt) {
        int row = m0 + mt*16 + lm;
        af[mt] = *(const bf16x8*)(&As[row*64 + (((kk8 + lq) ^ (row & 7)) << 3)]);
      }
#pragma unroll
      for (int nt = 0; nt < 8; ++nt) {
        int row = n0 + nt*16 + lm;
        bfr[nt] = *(const bf16x8*)(&Bs[row*64 + (((kk8 + lq) ^ (row & 7)) << 3)]);
      }
#pragma unroll
      for (int mt = 0; mt < 2; ++mt)
#pragma unroll
        for (int nt = 0; nt < 8; ++nt)
          acc[mt][nt] = __builtin_amdgcn_mfma_f32_16x16x32_bf16(
              af[mt], bfr[nt], acc[mt][nt], 0, 0, 0);
    }
  }
#pragma unroll
  for (int p = 0; p < 4; ++p) {
#pragma unroll
    for (int m = 8; m >= 1; m >>= 1) {
      s1[p] += __shfl_xor(s1[p], m, 16);
      s2[p] += __shfl_xor(s2[p], m, 16);
    }
  }
  if (seg == 0) {
#pragma unroll
    for (int p = 0; p < 4; ++p) {
      int row = p*16 + g16;
      float m = s1[p]*(1.f/768.f);
      meanS[row] = m;
      varArr[r0 + row] = s2[p]*(1.f/768.f) - m*m;
    }
  }
  __syncthreads();
#pragma unroll
  for (int nt = 0; nt < 8; ++nt) {
    int jg = n0 + nt*16 + lm;
    float gs = gsum[jg];
#pragma unroll
    for (int mt = 0; mt < 2; ++mt) {
#pragma unroll
      for (int reg = 0; reg < 4; ++reg) {
        int rl = m0 + mt*16 + lq*4 + reg;
        KVb[(size_t)(r0 + rl)*256 + jg] = f2bf(acc[mt][nt][reg] - meanS[rl]*gs);
      }
    }
  }
}

// ---- 3. slots init + LN + q (iter 0), MFMA; zeroes U/Ssum ----
__global__ __launch_bounds__(256, 1) void slots_init_q_k(
    const float* __restrict__ ps, const float* __restrict__ eps,
    const float* __restrict__ g_s, const float* __restrict__ b_s,
    const unsigned short* __restrict__ Wqbf, const float* __restrict__ biasArr,
    float* __restrict__ slots, float* __restrict__ qg, float* __restrict__ qkb,
    float* __restrict__ Ssum, float* __restrict__ U)
{
  __shared__ unsigned short Fsn[2048];
  __shared__ float qkbL[16];
  int R0 = blockIdx.x*16;
  int t = threadIdx.x;
  int w = t >> 6, ln = t & 63, lm = ln & 15, lq = ln >> 4;
  if (t < 16) qkbL[t] = 0.f;
  {
    int r = t >> 4, dseg = t & 15, ds8 = dseg*8;
    int row = R0 + r, bk = row >> 1;
    float xv[8]; float s1 = 0.f, s2 = 0.f;
#pragma unroll
    for (int j = 0; j < 8; ++j) {
      int d = ds8 + j;
      float x = ps[bk*128 + d] + 0.01f*eps[row*128 + d];
      slots[row*128 + d] = x;
      U[row*128 + d] = 0.f;
      xv[j] = x; s1 += x; s2 += x*x;
    }
#pragma unroll
    for (int m = 8; m >= 1; m >>= 1) {
      s1 += __shfl_xor(s1, m, 16);
      s2 += __shfl_xor(s2, m, 16);
    }
    float mean = s1*(1.f/128.f);
    float var = s2*(1.f/128.f) - mean*mean;
    float rstd = rsqrtf(var + 1e-5f);
    float sv[8];
#pragma unroll
    for (int j = 0; j < 8; ++j) {
      int d = ds8 + j;
      sv[j] = (xv[j] - mean)*rstd*g_s[d] + b_s[d];
    }
    int fa = ((dseg >> 2)*64 + (dseg & 3)*16 + r)*8;
    *(uint4*)&Fsn[fa] = make_uint4(pack2(sv[0],sv[1]), pack2(sv[2],sv[3]),
                                   pack2(sv[4],sv[5]), pack2(sv[6],sv[7]));
  }
  __syncthreads();
  {
    bf16x8 af[4];
#pragma unroll
    for (int kc = 0; kc < 4; ++kc)
      af[kc] = *(const bf16x8*)(&Fsn[(kc*64 + ln)*8]);
    float pr[4] = {0.f, 0.f, 0.f, 0.f};
#pragma unroll
    for (int i = 0; i < 2; ++i) {
      int n0 = w*32 + i*16;
      f32x4 acc = f32x4{0.f,0.f,0.f,0.f};
#pragma unroll
      for (int kc = 0; kc < 4; ++kc) {
        bf16x8 bw = *(const bf16x8*)(&Wqbf[(size_t)(n0+lm)*128 + kc*32 + lq*8]);
        acc = __builtin_amdgcn_mfma_f32_16x16x32_bf16(af[kc], bw, acc, 0,0,0);
      }
      int n = n0 + lm;
      float bk_ = biasArr[n];
#pragma unroll
      for (int reg = 0; reg < 4; ++reg) {
        int row = lq*4 + reg;
        qg[(size_t)(R0 + row)*128 + n] = acc[reg];
        pr[reg] += acc[reg]*bk_;
      }
    }
#pragma unroll
    for (int reg = 0; reg < 4; ++reg) {
#pragma unroll
      for (int m = 8; m >= 1; m >>= 1) pr[reg] += __shfl_xor(pr[reg], m, 16);
    }
    if (lm == 0) {
#pragma unroll
      for (int reg = 0; reg < 4; ++reg)
        atomicAdd(&qkbL[lq*4 + reg], pr[reg]);
    }
  }
  __syncthreads();
  if (t < 16) { qkb[R0 + t] = qkbL[t]; Ssum[R0 + t] = 0.f; }
}

// ---- 4. fused attention iteration (bf16 KV; U via atomics) ----
__global__ __launch_bounds__(256) void attn_fused_k(
    const unsigned short* __restrict__ KVb, const float* __restrict__ qg,
    const float* __restrict__ qkb, const float* __restrict__ varArr,
    const float* __restrict__ denomArr, const float* __restrict__ pm,
    float* __restrict__ U, float* __restrict__ Ssum,
    float* __restrict__ outG, int last)
{
  __shared__ float KVs[32*260];
  __shared__ float qs[2048];
  __shared__ float was[16*33];
  __shared__ float qkbs[16];
  int bi = blockIdx.x;
  int b = bi & 7, ch = bi >> 3;
  int t = threadIdx.x;
#pragma unroll
  for (int s = 0; s < 2; ++s)
    ((float4*)qs)[s*256 + t] = ((const float4*)(qg + b*2048))[s*256 + t];
  if (t < 16) qkbs[t] = qkb[b*16 + t];
  int p = t >> 5, nl = t & 31;
  int iu = t >> 4, dg = t & 15;
  int bk = b*8 + p;
  float den = denomArr[bk];
  float acc8[8];
#pragma unroll
  for (int j = 0; j < 8; ++j) acc8[j] = 0.f;
  float sA0 = 0.f, sA1 = 0.f;
  const float* q0 = qs + (p*2)*128;
  const float* q1 = q0 + 128;
  __syncthreads();
  float qb0 = qkbs[p*2], qb1 = qkbs[p*2 + 1];
  for (int sub = 0; sub < 4; ++sub) {
    int n0 = ch*128 + sub*32;
    if (sub) __syncthreads();
    {
      int nn = t >> 3, jj = t & 7;
#pragma unroll
      for (int s = 0; s < 4; ++s) {
        int col8 = jj + s*8;
        u16x8 kv8 = *(const u16x8*)&KVb[((size_t)(b*4096 + n0 + nn))*256 + col8*8];
        float4 f0, f1;
        f0.x = bf2f(kv8[0]); f0.y = bf2f(kv8[1]); f0.z = bf2f(kv8[2]); f0.w = bf2f(kv8[3]);
        f1.x = bf2f(kv8[4]); f1.y = bf2f(kv8[5]); f1.z = bf2f(kv8[6]); f1.w = bf2f(kv8[7]);
        *(float4*)&KVs[nn*260 + col8*8] = f0;
        *(float4*)&KVs[nn*260 + col8*8 + 4] = f1;
      }
    }
    __syncthreads();
    float d0 = 0.f, d1 = 0.f;
    const float* kr = KVs + nl*260;
#pragma unroll 8
    for (int j4 = 0; j4 < 32; ++j4) {
      float4 kv = *(const float4*)(kr + j4*4);
      float4 qa = *(const float4*)(q0 + j4*4);
      float4 qb = *(const float4*)(q1 + j4*4);
      d0 += kv.x*qa.x + kv.y*qa.y + kv.z*qa.z + kv.w*qa.w;
      d1 += kv.x*qb.x + kv.y*qb.y + kv.z*qb.z + kv.w*qb.w;
    }
    int n = n0 + nl;
    float pmv = pm[(size_t)bk*4096 + n];
    float c = (den > 1e-6f) ? (pmv/(den + 1e-6f)) : 1.f;
    float vv = varArr[b*4096 + n];
    float al = c*rsqrtf(c*c*vv + 1e-5f);
    float dd0 = SCALE_*(al*d0 + qb0);
    float dd1 = SCALE_*(al*d1 + qb1);
    float mx = fmaxf(dd0, dd1);
    float e0 = expf(dd0 - mx), e1 = expf(dd1 - mx);
    float inv = 1.f/(e0 + e1);
    float o0 = e0*inv + 1e-8f;
    float o1 = e1*inv + 1e-8f;
    sA0 += o0; sA1 += o1;
    was[(p*2)*33 + nl] = o0*al;
    was[(p*2 + 1)*33 + nl] = o1*al;
    if (last) {
      outG[((size_t)(bk*2))*4096 + n] = o0*pmv;
      outG[((size_t)(bk*2 + 1))*4096 + n] = o1*pmv;
    }
    __syncthreads();
    const float* vb = KVs + 128 + dg*8;
    const float* wr = was + iu*33;
#pragma unroll 8
    for (int nn = 0; nn < 32; ++nn) {
      float wv = wr[nn];
      float4 v0 = *(const float4*)(vb + nn*260);
      float4 v1 = *(const float4*)(vb + nn*260 + 4);
      acc8[0] += wv*v0.x; acc8[1] += wv*v0.y; acc8[2] += wv*v0.z; acc8[3] += wv*v0.w;
      acc8[4] += wv*v1.x; acc8[5] += wv*v1.y; acc8[6] += wv*v1.z; acc8[7] += wv*v1.w;
    }
  }
#pragma unroll
  for (int m = 16; m >= 1; m >>= 1) {
    sA0 += __shfl_xor(sA0, m, 32);
    sA1 += __shfl_xor(sA1, m, 32);
  }
  if (nl == 0) {
    atomicAdd(&Ssum[bk*2], sA0);
    atomicAdd(&Ssum[bk*2 + 1], sA1);
  }
  float* ur = U + (size_t)(b*16 + iu)*128 + dg*8;
#pragma unroll
  for (int j = 0; j < 8; ++j) atomicAdd(ur + j, acc8[j]);
}

// ---- 5. GRU + MLP + next-iter q (MFMA); re-zeroes U/Ssum when !last ----
__global__ __launch_bounds__(256, 1) void gru_mlp_q_k(
    const float* __restrict__ Uin, const float* __restrict__ Ssum,
    const float* __restrict__ biasArr,
    const unsigned short* __restrict__ Wihbf, const unsigned short* __restrict__ Whhbf,
    const float* __restrict__ bih, const float* __restrict__ bhh,
    const float* __restrict__ mlp_g, const float* __restrict__ mlp_b,
    const unsigned short* __restrict__ W1bf, const float* __restrict__ b1,
    const unsigned short* __restrict__ Wm2bf, const float* __restrict__ b2,
    const float* __restrict__ ln_s_g, const float* __restrict__ ln_s_b,
    const unsigned short* __restrict__ Wqbf,
    float* __restrict__ slots, float* __restrict__ qg, float* __restrict__ qkb,
    float* __restrict__ SsumW, float* __restrict__ Uw,
    float* __restrict__ outObj, int last)
{
  __shared__ unsigned short FXx[2048], FXh[2048], Fhn[2048], Fsn[2048];
  __shared__ unsigned short Ft1[8192];
  __shared__ float G_rz[16*256];
  __shared__ float G_in[16*128];
  __shared__ float G_hn[16*128];
  __shared__ float hs_[16*128];
  __shared__ float os_[16*128];
  __shared__ float qkbL[16];

  int R0 = blockIdx.x*16;
  int t = threadIdx.x;
  int w = t >> 6, ln = t & 63;
  int lm = ln & 15, lq = ln >> 4;

  // ---- phase A ----
  {
    int r = t >> 4, dseg = t & 15, ds8 = dseg*8;
    int R = R0 + r;
    const float* up = Uin + (size_t)R*128 + ds8;
    float4 u0 = *(const float4*)(up);
    float4 u1 = *(const float4*)(up + 4);
    float Sv = 1.f/Ssum[R];
    float4 bv0 = *(const float4*)(biasArr + 128 + ds8);
    float4 bv1 = *(const float4*)(biasArr + 132 + ds8);
    float xv[8];
    xv[0]=u0.x*Sv+bv0.x; xv[1]=u0.y*Sv+bv0.y; xv[2]=u0.z*Sv+bv0.z; xv[3]=u0.w*Sv+bv0.w;
    xv[4]=u1.x*Sv+bv1.x; xv[5]=u1.y*Sv+bv1.y; xv[6]=u1.z*Sv+bv1.z; xv[7]=u1.w*Sv+bv1.w;
    if (!last) {
      *(float4*)(Uw + (size_t)R*128 + ds8) = make_float4(0.f,0.f,0.f,0.f);
      *(float4*)(Uw + (size_t)R*128 + ds8 + 4) = make_float4(0.f,0.f,0.f,0.f);
    }
    float4 h0 = *(const float4*)(slots + (size_t)R*128 + ds8);
    float4 h1 = *(const float4*)(slots + (size_t)R*128 + ds8 + 4);
    *(float4*)(hs_ + r*128 + ds8) = h0;
    *(float4*)(hs_ + r*128 + ds8 + 4) = h1;
    int fa = ((dseg >> 2)*64 + (dseg & 3)*16 + r)*8;
    *(uint4*)&FXx[fa] = make_uint4(pack2(xv[0],xv[1]), pack2(xv[2],xv[3]),
                                   pack2(xv[4],xv[5]), pack2(xv[6],xv[7]));
    *(uint4*)&FXh[fa] = make_uint4(pack2(h0.x,h0.y), pack2(h0.z,h0.w),
                                   pack2(h1.x,h1.y), pack2(h1.z,h1.w));
    if (t < 16) qkbL[t] = 0.f;
  }
  __syncthreads();

  // ---- phase B: GRU gemms ----
  {
    bf16x8 ax[4], ah[4];
#pragma unroll
    for (int kc = 0; kc < 4; ++kc) {
      ax[kc] = *(const bf16x8*)(&FXx[(kc*64 + ln)*8]);
      ah[kc] = *(const bf16x8*)(&FXh[(kc*64 + ln)*8]);
    }
    if (w < 2) {
#pragma unroll
      for (int i = 0; i < 8; ++i) {
        int n0 = (w*8 + i)*16;
        f32x4 acc = f32x4{0.f,0.f,0.f,0.f};
#pragma unroll
        for (int kc = 0; kc < 4; ++kc) {
          bf16x8 bi_ = *(const bf16x8*)(&Wihbf[(size_t)(n0+lm)*128 + kc*32 + lq*8]);
          acc = __builtin_amdgcn_mfma_f32_16x16x32_bf16(ax[kc], bi_, acc, 0,0,0);
        }
#pragma unroll
        for (int kc = 0; kc < 4; ++kc) {
          bf16x8 bh_ = *(const bf16x8*)(&Whhbf[(size_t)(n0+lm)*128 + kc*32 + lq*8]);
          acc = __builtin_amdgcn_mfma_f32_16x16x32_bf16(ah[kc], bh_, acc, 0,0,0);
        }
#pragma unroll
        for (int reg = 0; reg < 4; ++reg)
          G_rz[(lq*4+reg)*256 + n0 + lm] = acc[reg];
      }
    } else if (w == 2) {
#pragma unroll
      for (int i = 0; i < 8; ++i) {
        int n0 = 256 + i*16;
        f32x4 acc = f32x4{0.f,0.f,0.f,0.f};
#pragma unroll
        for (int kc = 0; kc < 4; ++kc) {
          bf16x8 bi_ = *(const bf16x8*)(&Wihbf[(size_t)(n0+lm)*128 + kc*32 + lq*8]);
          acc = __builtin_amdgcn_mfma_f32_16x16x32_bf16(ax[kc], bi_, acc, 0,0,0);
        }
#pragma unroll
        for (int reg = 0; reg < 4; ++reg)
          G_in[(lq*4+reg)*128 + i*16 + lm] = acc[reg];
      }
    } else {
#pragma unroll
      for (int i = 0; i < 8; ++i) {
        int n0 = 256 + i*16;
        f32x4 acc = f32x4{0.f,0.f,0.f,0.f};
#pragma unroll
        for (int kc = 0; kc < 4; ++kc) {
          bf16x8 bh_ = *(const bf16x8*)(&Whhbf[(size_t)(n0+lm)*128 + kc*32 + lq*8]);
          acc = __builtin_amdgcn_mfma_f32_16x16x32_bf16(ah[kc], bh_, acc, 0,0,0);
        }
#pragma unroll
        for (int reg = 0; reg < 4; ++reg)
          G_hn[(lq*4+reg)*128 + i*16 + lm] = acc[reg];
      }
    }
  }
  __syncthreads();

  // ---- phase C: elementwise GRU + LN -> Fhn ----
  {
    int r = t >> 4, dseg = t & 15, ds8 = dseg*8;
    float hp[8];
    float s1 = 0.f, s2 = 0.f;
#pragma unroll
    for (int j = 0; j < 8; ++j) {
      int d = ds8 + j;
      float rg = G_rz[r*256 + d] + bih[d] + bhh[d];
      float zg = G_rz[r*256 + 128 + d] + bih[128+d] + bhh[128+d];
      float ing = G_in[r*128 + d] + bih[256+d];
      float hng = G_hn[r*128 + d] + bhh[256+d];
      float rv = 1.f/(1.f + expf(-rg));
      float zv = 1.f/(1.f + expf(-zg));
      float nv = tanhf(ing + rv*hng);
      float h0 = hs_[r*128 + d];
      float h = (1.f - zv)*nv + zv*h0;
      hp[j] = h;
      s1 += h; s2 += h*h;
    }
#pragma unroll
    for (int m = 8; m >= 1; m >>= 1) {
      s1 += __shfl_xor(s1, m, 16);
      s2 += __shfl_xor(s2, m, 16);
    }
    float mean = s1*(1.f/128.f);
    float var = s2*(1.f/128.f) - mean*mean;
    float rstd = rsqrtf(var + 1e-5f);
    float hv[8];
#pragma unroll
    for (int j = 0; j < 8; ++j) {
      int d = ds8 + j;
      hv[j] = (hp[j] - mean)*rstd*mlp_g[d] + mlp_b[d];
    }
    int fa = ((dseg >> 2)*64 + (dseg & 3)*16 + r)*8;
    *(uint4*)&Fhn[fa] = make_uint4(pack2(hv[0],hv[1]), pack2(hv[2],hv[3]),
                                   pack2(hv[4],hv[5]), pack2(hv[6],hv[7]));
  }
  __syncthreads();

  // ---- phase D: MLP1 + gelu -> Ft1 ----
  {
    bf16x8 af[4];
#pragma unroll
    for (int kc = 0; kc < 4; ++kc)
      af[kc] = *(const bf16x8*)(&Fhn[(kc*64 + ln)*8]);
#pragma unroll
    for (int i = 0; i < 8; ++i) {
      int n0 = (w*8 + i)*16;
      f32x4 acc = f32x4{0.f,0.f,0.f,0.f};
#pragma unroll
      for (int kc = 0; kc < 4; ++kc) {
        bf16x8 bw = *(const bf16x8*)(&W1bf[(size_t)(n0+lm)*128 + kc*32 + lq*8]);
        acc = __builtin_amdgcn_mfma_f32_16x16x32_bf16(af[kc], bw, acc, 0,0,0);
      }
      int kdim = n0 + lm;
      float bb = b1[kdim];
      int kc2 = kdim >> 5;
      int sub = (kdim >> 3) & 3;
      int jj = kdim & 7;
#pragma unroll
      for (int reg = 0; reg < 4; ++reg) {
        float v = acc[reg] + bb;
        float gel = 0.5f*v*(1.f + erff(v*0.70710678118654752f));
        Ft1[(kc2*64 + sub*16 + lq*4 + reg)*8 + jj] = f2bf(gel);
      }
    }
  }
  __syncthreads();

  // ---- phase E: MLP2 -> slots ----
  {
#pragma unroll
    for (int i = 0; i < 2; ++i) {
      int n0 = w*32 + i*16;
      f32x4 acc = f32x4{0.f,0.f,0.f,0.f};
#pragma unroll
      for (int kc = 0; kc < 16; ++kc) {
        bf16x8 af = *(const bf16x8*)(&Ft1[(kc*64 + ln)*8]);
        bf16x8 bw = *(const bf16x8*)(&Wm2bf[(size_t)(n0+lm)*512 + kc*32 + lq*8]);
        acc = __builtin_amdgcn_mfma_f32_16x16x32_bf16(af, bw, acc, 0,0,0);
      }
      int n = n0 + lm;
      float bb = b2[n];
#pragma unroll
      for (int reg = 0; reg < 4; ++reg) {
        int row = lq*4 + reg;
        float o = acc[reg] + bb;
        slots[(size_t)(R0 + row)*128 + n] = o;
        os_[row*128 + n] = o;
        if (last) outObj[(size_t)(R0 + row)*128 + n] = o;
      }
    }
  }

  if (last) return;

  __syncthreads();
  // ---- phase F1: LN(slots) -> Fsn ----
  {
    int r = t >> 4, dseg = t & 15, ds8 = dseg*8;
    float ov[8];
    float s1 = 0.f, s2 = 0.f;
#pragma unroll
    for (int j = 0; j < 8; ++j) {
      float o = os_[r*128 + ds8 + j];
      ov[j] = o; s1 += o; s2 += o*o;
    }
#pragma unroll
    for (int m = 8; m >= 1; m >>= 1) {
      s1 += __shfl_xor(s1, m, 16);
      s2 += __shfl_xor(s2, m, 16);
    }
    float mean = s1*(1.f/128.f);
    float var = s2*(1.f/128.f) - mean*mean;
    float rstd = rsqrtf(var + 1e-5f);
    float sv[8];
#pragma unroll
    for (int j = 0; j < 8; ++j) {
      int d = ds8 + j;
      sv[j] = (ov[j] - mean)*rstd*ln_s_g[d] + ln_s_b[d];
    }
    int fa = ((dseg >> 2)*64 + (dseg & 3)*16 + r)*8;
    *(uint4*)&Fsn[fa] = make_uint4(pack2(sv[0],sv[1]), pack2(sv[2],sv[3]),
                                   pack2(sv[4],sv[5]), pack2(sv[6],sv[7]));
  }
  __syncthreads();

  // ---- phase F2: q + qkb ----
  {
    bf16x8 af[4];
#pragma unroll
    for (int kc = 0; kc < 4; ++kc)
      af[kc] = *(const bf16x8*)(&Fsn[(kc*64 + ln)*8]);
    float pr[4] = {0.f, 0.f, 0.f, 0.f};
#pragma unroll
    for (int i = 0; i < 2; ++i) {
      int n0 = w*32 + i*16;
      f32x4 acc = f32x4{0.f,0.f,0.f,0.f};
#pragma unroll
      for (int kc = 0; kc < 4; ++kc) {
        bf16x8 bw = *(const bf16x8*)(&Wqbf[(size_t)(n0+lm)*128 + kc*32 + lq*8]);
        acc = __builtin_amdgcn_mfma_f32_16x16x32_bf16(af[kc], bw, acc, 0,0,0);
      }
      int n = n0 + lm;
      float bk_ = biasArr[n];
#pragma unroll
      for (int reg = 0; reg < 4; ++reg) {
        int row = lq*4 + reg;
        qg[(size_t)(R0 + row)*128 + n] = acc[reg];
        pr[reg] += acc[reg]*bk_;
      }
    }
#pragma unroll
    for (int reg = 0; reg < 4; ++reg) {
#pragma unroll
      for (int m = 8; m >= 1; m >>= 1) pr[reg] += __shfl_xor(pr[reg], m, 16);
    }
    if (lm == 0) {
#pragma unroll
      for (int reg = 0; reg < 4; ++reg)
        atomicAdd(&qkbL[lq*4 + reg], pr[reg]);
    }
  }
  __syncthreads();
  if (t < 16) {
    qkb[R0 + t] = qkbL[t];
    SsumW[R0 + t] = 0.f;
  }
}

extern "C" void kernel_launch(void* const* d_in, const int* in_sizes, int n_in,
                              void* d_out, int out_size, void* d_ws, size_t ws_size,
                              hipStream_t stream) {
  const float* tokens = (const float*)d_in[0];
  const float* pslots = (const float*)d_in[1];
  const float* pmasks = (const float*)d_in[2];
  const float* eps    = (const float*)d_in[3];
  const float* ln_in_g= (const float*)d_in[4];
  const float* ln_in_b= (const float*)d_in[5];
  const float* ln_s_g = (const float*)d_in[6];
  const float* ln_s_b = (const float*)d_in[7];
  const float* Wq     = (const float*)d_in[8];
  const float* Wk     = (const float*)d_in[9];
  const float* Wv     = (const float*)d_in[10];
  const float* Wih    = (const float*)d_in[11];
  const float* Whh    = (const float*)d_in[12];
  const float* bih    = (const float*)d_in[13];
  const float* bhh    = (const float*)d_in[14];
  const float* mlp_g  = (const float*)d_in[15];
  const float* mlp_b  = (const float*)d_in[16];
  const float* W1     = (const float*)d_in[17];
  const float* b1     = (const float*)d_in[18];
  const float* W2     = (const float*)d_in[19];
  const float* b2     = (const float*)d_in[20];
  float* ws  = (float*)d_ws;
  float* out = (float*)d_out;
  unsigned short* wkvbf = (unsigned short*)(ws + OFF_WKVBF);
  unsigned short* wqbf  = (unsigned short*)(ws + OFF_WQBF);
  unsigned short* wihbf = (unsigned short*)(ws + OFF_WIHBF);
  unsigned short* whhbf = (unsigned short*)(ws + OFF_WHHBF);
  unsigned short* w1bf  = (unsigned short*)(ws + OFF_W1BF);
  unsigned short* wm2bf = (unsigned short*)(ws + OFF_WM2BF);
  unsigned short* kvb   = (unsigned short*)(ws + OFF_KVB);

  prep_all_k<<<1088, 256, 0, stream>>>(Wk, Wv, ln_in_g, ln_in_b,
                                       Wq, Wih, Whh, W1, W2, pmasks,
                                       wkvbf, ws + OFF_GSUM, ws + OFF_BIAS,
                                       wqbf, wihbf, whhbf, w1bf, wm2bf,
                                       ws + OFF_DENOM);
  gemm_kv_k<<<512, 256, 0, stream>>>(tokens, wkvbf, ws + OFF_GSUM,
                                     kvb, ws + OFF_VAR);
  slots_init_q_k<<<8, 256, 0, stream>>>(pslots, eps, ln_s_g, ln_s_b,
                                        wqbf, ws + OFF_BIAS,
                                        ws + OFF_SLOTS, ws + OFF_Q,
                                        ws + OFF_QKB, ws + OFF_SSUM,
                                        ws + OFF_U);
  for (int it = 0; it < 3; ++it) {
    int last = (it == 2);
    attn_fused_k<<<256, 256, 0, stream>>>(kvb, ws + OFF_Q, ws + OFF_QKB,
                                          ws + OFF_VAR, ws + OFF_DENOM, pmasks,
                                          ws + OFF_U, ws + OFF_SSUM,
                                          out + 16384, last);
    gru_mlp_q_k<<<8, 256, 0, stream>>>(ws + OFF_U, ws + OFF_SSUM,
                                       ws + OFF_BIAS, wihbf, whhbf, bih, bhh,
                                       mlp_g, mlp_b, w1bf, b1, wm2bf, b2,
                                       ln_s_g, ln_s_b, wqbf,
                                       ws + OFF_SLOTS, ws + OFF_Q, ws + OFF_QKB,
                                       ws + OFF_SSUM, ws + OFF_U, out, last);
  }
}

// Round 5
// 380.324 us; speedup vs baseline: 1.0459x; 1.0459x over previous
//
#include <hip/hip_runtime.h>
#include <math.h>

#define SCALE_ 0.08838834764831843f

typedef __attribute__((ext_vector_type(8))) short bf16x8;
typedef __attribute__((ext_vector_type(4))) float f32x4;
typedef __attribute__((ext_vector_type(8))) unsigned short u16x8;

// ---- workspace layout (float offsets) ----
static const size_t OFF_VAR   = 0;        // 32768
static const size_t OFF_DENOM = 32768;    // 64
static const size_t OFF_GSUM  = 32832;    // 256
static const size_t OFF_BIAS  = 33088;    // 256
static const size_t OFF_QKB   = 33344;    // 128
static const size_t OFF_SSUM  = 33472;    // 128
static const size_t OFF_SLOTS = 33600;    // 16384
static const size_t OFF_Q     = 49984;    // 16384
static const size_t OFF_WQBF  = 66368;    // 8192 fl Wq[128][128] bf16
static const size_t OFF_WIHBF = 74560;    // 24576 fl Wih[384][128] bf16
static const size_t OFF_WHHBF = 99136;    // 24576 fl Whh[384][128] bf16
static const size_t OFF_W1BF  = 123712;   // 32768 fl W1[512][128] bf16
static const size_t OFF_WM2BF = 156480;   // 32768 fl W2[128][512] bf16
static const size_t OFF_WKVBF = 189248;   // 98304 fl (196608 bf16) [256][768] plain
static const size_t OFF_UPART = 287552;   // 524288 [4096][128] partials
static const size_t OFF_KVB   = 811840;   // 2097152 fl (4194304 bf16) [b][n][256]

__device__ __forceinline__ float wred64(float v) {
#pragma unroll
  for (int off = 32; off > 0; off >>= 1) v += __shfl_xor(v, off, 64);
  return v;
}

__device__ __forceinline__ unsigned short f2bf(float f) {
  unsigned u = __float_as_uint(f);
  unsigned r = (u + 0x7fffu + ((u >> 16) & 1u)) >> 16;
  return (unsigned short)r;
}

__device__ __forceinline__ unsigned pack2(float a, float b) {
  return (unsigned)f2bf(a) | ((unsigned)f2bf(b) << 16);
}

__device__ __forceinline__ float bf2f(unsigned short s) {
  return __uint_as_float((unsigned)s << 16);
}

// ---- 1. merged prep ----
__global__ __launch_bounds__(256) void prep_all_k(
    const float* __restrict__ Wk, const float* __restrict__ Wv,
    const float* __restrict__ g, const float* __restrict__ bb,
    const float* __restrict__ Wq, const float* __restrict__ Wih,
    const float* __restrict__ Whh, const float* __restrict__ W1,
    const float* __restrict__ W2, const float* __restrict__ pm,
    unsigned short* __restrict__ wkv, float* __restrict__ gsum,
    float* __restrict__ biasArr,
    unsigned short* __restrict__ Wqbf, unsigned short* __restrict__ Wihbf,
    unsigned short* __restrict__ Whhbf, unsigned short* __restrict__ W1bf,
    unsigned short* __restrict__ Wm2bf, float* __restrict__ denomArr)
{
  __shared__ float red4[4];
  int bi = blockIdx.x, t = threadIdx.x;
  if (bi < 64) {
    int j = bi*4 + (t >> 6), lane = t & 63;
    const float* w = (j < 128) ? (Wk + (size_t)j*768) : (Wv + (size_t)(j-128)*768);
    float gs = 0.f, bs = 0.f;
#pragma unroll
    for (int s = 0; s < 12; ++s) {
      int dd = lane + s*64;
      float wv = w[dd], gv = g[dd];
      gs += gv*wv; bs += bb[dd]*wv;
      wkv[(size_t)j*768 + dd] = f2bf(wv*gv);
    }
    gs = wred64(gs); bs = wred64(bs);
    if (lane == 0) { gsum[j] = gs; biasArr[j] = bs; }
  } else if (bi < 128) {
    int idx = (bi-64)*256 + t;  Wqbf[idx]  = f2bf(Wq[idx]);
  } else if (bi < 320) {
    int idx = (bi-128)*256 + t; Wihbf[idx] = f2bf(Wih[idx]);
  } else if (bi < 512) {
    int idx = (bi-320)*256 + t; Whhbf[idx] = f2bf(Whh[idx]);
  } else if (bi < 768) {
    int idx = (bi-512)*256 + t; W1bf[idx]  = f2bf(W1[idx]);
  } else if (bi < 1024) {
    int idx = (bi-768)*256 + t; Wm2bf[idx] = f2bf(W2[idx]);
  } else {
    int bk = bi - 1024;
    float s = 0.f;
#pragma unroll
    for (int k = 0; k < 16; ++k) s += pm[bk*4096 + t + k*256];
    s = wred64(s);
    if ((t & 63) == 0) red4[t >> 6] = s;
    __syncthreads();
    if (t == 0) denomArr[bk] = (red4[0]+red4[1]+red4[2]+red4[3])*(1.f/4096.f);
  }
}

// ---- 2. pipelined MFMA GEMM: tokens[32768,768] -> KVb bf16 [b][n][256] ----
// grid 512: block = 64 rows x 256 cols, 4 waves each 16 rows x 256 cols.
// B: LDS double-buffer via global_load_lds, raw s_barrier + vmcnt(6) (never 0).
// A: direct global->VGPR fragments, prefetched 1 step; stats via shuffles.
#define DMA_B(kstep, buf) \
  { int k0_ = (kstep)*32; \
    _Pragma("unroll") \
    for (int s_ = 0; s_ < 4; ++s_) { \
      int nb_ = w*64 + s_*16; \
      __builtin_amdgcn_global_load_lds( \
        (const __attribute__((address_space(1))) void*) \
          (wkv + (size_t)(nb_ + nrow)*768 + k0_ + gsw*8), \
        (__attribute__((address_space(3))) void*)(Bs + (buf)*8192 + nb_*32), \
        16, 0, 0); \
    } }

__global__ __launch_bounds__(256) void gemm_kv_k(
    const float* __restrict__ tokens, const unsigned short* __restrict__ wkv,
    const float* __restrict__ gsum, unsigned short* __restrict__ KVb,
    float* __restrict__ varArr)
{
  __shared__ unsigned short Bs[2*8192];   // 2 x [256 rows][32 k] bf16, granule-swizzled
  int r0 = blockIdx.x*64;
  int t = threadIdx.x;
  int w = t >> 6, lane = t & 63;
  int lm = lane & 15, lq = lane >> 4;
  int nrow = lane >> 2;
  int gsw = (lane & 3) ^ ((lane >> 3) & 3);      // DMA source granule permute
  int nswz = lq ^ ((lm >> 1) & 3);               // ds_read granule position

  const float* aptr = tokens + (size_t)(r0 + w*16 + lm)*768 + lq*8;

  f32x4 acc[16];
#pragma unroll
  for (int c = 0; c < 16; ++c) acc[c] = f32x4{0.f, 0.f, 0.f, 0.f};
  float s1 = 0.f, s2 = 0.f;

  float4 A0[2], A1[2];
  // prologue
  DMA_B(0, 0);
  A0[0] = *(const float4*)(aptr);
  A1[0] = *(const float4*)(aptr + 4);
  DMA_B(1, 1);
  __builtin_amdgcn_s_waitcnt(0x0F76);   // vmcnt(6): dma(0) done
  __builtin_amdgcn_s_barrier();

#pragma unroll
  for (int k = 0; k < 24; ++k) {
    const int kb = k & 1, kn = kb ^ 1;
    float4 x0 = A0[kb], x1 = A1[kb];
    s1 += x0.x + x0.y + x0.z + x0.w + x1.x + x1.y + x1.z + x1.w;
    s2 += x0.x*x0.x + x0.y*x0.y + x0.z*x0.z + x0.w*x0.w
        + x1.x*x1.x + x1.y*x1.y + x1.z*x1.z + x1.w*x1.w;
    unsigned u0 = pack2(x0.x, x0.y), u1 = pack2(x0.z, x0.w);
    unsigned u2 = pack2(x1.x, x1.y), u3 = pack2(x1.z, x1.w);
    bf16x8 afrag;
    { uint4 tmp = make_uint4(u0, u1, u2, u3);
      afrag = *(bf16x8*)&tmp; }
    if (k < 23) {
      A0[kn] = *(const float4*)(aptr + (k+1)*32);
      A1[kn] = *(const float4*)(aptr + (k+1)*32 + 4);
    }
    const unsigned short* bsr = Bs + kb*8192;
#pragma unroll
    for (int nt = 0; nt < 16; ++nt) {
      bf16x8 bfr = *(const bf16x8*)(bsr + (nt*16 + lm)*32 + nswz*8);
      acc[nt] = __builtin_amdgcn_mfma_f32_16x16x32_bf16(afrag, bfr, acc[nt], 0, 0, 0);
    }
    if (k < 23) {
      __builtin_amdgcn_s_barrier();      // everyone done reading buf kb
      if (k < 22) {
        DMA_B(k+2, kb);
        __builtin_amdgcn_s_waitcnt(0x0F76);  // vmcnt(6): dma(k+1) done
      } else {
        __builtin_amdgcn_s_waitcnt(0x0F72);  // vmcnt(2): dma(23) done
      }
      __builtin_amdgcn_s_barrier();      // buf kn ready for all
    }
  }

  // stats: reduce over the 4 lq copies of each row
  s1 += __shfl_xor(s1, 16, 64); s1 += __shfl_xor(s1, 32, 64);
  s2 += __shfl_xor(s2, 16, 64); s2 += __shfl_xor(s2, 32, 64);
  float mean = s1*(1.f/768.f);
  float var  = s2*(1.f/768.f) - mean*mean;
  if (lq == 0) varArr[r0 + w*16 + lm] = var;
  float meanR[4];
#pragma unroll
  for (int reg = 0; reg < 4; ++reg)
    meanR[reg] = __shfl(mean, lq*4 + reg, 64);   // wait: need row lq*4+reg of THIS wave: lanes 0-15 hold rows 0-15
#pragma unroll
  for (int nt = 0; nt < 16; ++nt) {
    int col = nt*16 + lm;
    float gs = gsum[col];
#pragma unroll
    for (int reg = 0; reg < 4; ++reg) {
      int row = r0 + w*16 + lq*4 + reg;
      KVb[(size_t)row*256 + col] = f2bf(acc[nt][reg] - meanR[reg]*gs);
    }
  }
}

// ---- 3. slots init + LN + q (iter 0), MFMA; zeroes Ssum ----
__global__ __launch_bounds__(256, 1) void slots_init_q_k(
    const float* __restrict__ ps, const float* __restrict__ eps,
    const float* __restrict__ g_s, const float* __restrict__ b_s,
    const unsigned short* __restrict__ Wqbf, const float* __restrict__ biasArr,
    float* __restrict__ slots, float* __restrict__ qg, float* __restrict__ qkb,
    float* __restrict__ Ssum)
{
  __shared__ unsigned short Fsn[2048];
  __shared__ float qkbL[16];
  int R0 = blockIdx.x*16;
  int t = threadIdx.x;
  int w = t >> 6, ln = t & 63, lm = ln & 15, lq = ln >> 4;
  if (t < 16) qkbL[t] = 0.f;
  {
    int r = t >> 4, dseg = t & 15, ds8 = dseg*8;
    int row = R0 + r, bk = row >> 1;
    float xv[8]; float s1 = 0.f, s2 = 0.f;
#pragma unroll
    for (int j = 0; j < 8; ++j) {
      int d = ds8 + j;
      float x = ps[bk*128 + d] + 0.01f*eps[row*128 + d];
      slots[row*128 + d] = x;
      xv[j] = x; s1 += x; s2 += x*x;
    }
#pragma unroll
    for (int m = 8; m >= 1; m >>= 1) {
      s1 += __shfl_xor(s1, m, 16);
      s2 += __shfl_xor(s2, m, 16);
    }
    float mean = s1*(1.f/128.f);
    float var = s2*(1.f/128.f) - mean*mean;
    float rstd = rsqrtf(var + 1e-5f);
    float sv[8];
#pragma unroll
    for (int j = 0; j < 8; ++j) {
      int d = ds8 + j;
      sv[j] = (xv[j] - mean)*rstd*g_s[d] + b_s[d];
    }
    int fa = ((dseg >> 2)*64 + (dseg & 3)*16 + r)*8;
    *(uint4*)&Fsn[fa] = make_uint4(pack2(sv[0],sv[1]), pack2(sv[2],sv[3]),
                                   pack2(sv[4],sv[5]), pack2(sv[6],sv[7]));
  }
  __syncthreads();
  {
    bf16x8 af[4];
#pragma unroll
    for (int kc = 0; kc < 4; ++kc)
      af[kc] = *(const bf16x8*)(&Fsn[(kc*64 + ln)*8]);
    float pr[4] = {0.f, 0.f, 0.f, 0.f};
#pragma unroll
    for (int i = 0; i < 2; ++i) {
      int n0 = w*32 + i*16;
      f32x4 acc = f32x4{0.f,0.f,0.f,0.f};
#pragma unroll
      for (int kc = 0; kc < 4; ++kc) {
        bf16x8 bw = *(const bf16x8*)(&Wqbf[(size_t)(n0+lm)*128 + kc*32 + lq*8]);
        acc = __builtin_amdgcn_mfma_f32_16x16x32_bf16(af[kc], bw, acc, 0,0,0);
      }
      int n = n0 + lm;
      float bk_ = biasArr[n];
#pragma unroll
      for (int reg = 0; reg < 4; ++reg) {
        int row = lq*4 + reg;
        qg[(size_t)(R0 + row)*128 + n] = acc[reg];
        pr[reg] += acc[reg]*bk_;
      }
    }
#pragma unroll
    for (int reg = 0; reg < 4; ++reg) {
#pragma unroll
      for (int m = 8; m >= 1; m >>= 1) pr[reg] += __shfl_xor(pr[reg], m, 16);
    }
    if (lm == 0) {
#pragma unroll
      for (int reg = 0; reg < 4; ++reg)
        atomicAdd(&qkbL[lq*4 + reg], pr[reg]);
    }
  }
  __syncthreads();
  if (t < 16) { qkb[R0 + t] = qkbL[t]; Ssum[R0 + t] = 0.f; }
}

// ---- 4. fused attention iteration (bf16 KV; U per-block partials) ----
__global__ __launch_bounds__(256) void attn_fused_k(
    const unsigned short* __restrict__ KVb, const float* __restrict__ qg,
    const float* __restrict__ qkb, const float* __restrict__ varArr,
    const float* __restrict__ denomArr, const float* __restrict__ pm,
    float* __restrict__ Upart, float* __restrict__ Ssum,
    float* __restrict__ outG, int last)
{
  __shared__ float KVs[32*260];
  __shared__ float qs[2048];
  __shared__ float was[16*33];
  __shared__ float qkbs[16];
  int bi = blockIdx.x;
  int b = bi & 7, ch = bi >> 3;
  int t = threadIdx.x;
#pragma unroll
  for (int s = 0; s < 2; ++s)
    ((float4*)qs)[s*256 + t] = ((const float4*)(qg + b*2048))[s*256 + t];
  if (t < 16) qkbs[t] = qkb[b*16 + t];
  int p = t >> 5, nl = t & 31;
  int iu = t >> 4, dg = t & 15;
  int bk = b*8 + p;
  float den = denomArr[bk];
  float acc8[8];
#pragma unroll
  for (int j = 0; j < 8; ++j) acc8[j] = 0.f;
  float sA0 = 0.f, sA1 = 0.f;
  const float* q0 = qs + (p*2)*128;
  const float* q1 = q0 + 128;
  __syncthreads();
  float qb0 = qkbs[p*2], qb1 = qkbs[p*2 + 1];
  for (int sub = 0; sub < 4; ++sub) {
    int n0 = ch*128 + sub*32;
    if (sub) __syncthreads();
    {
      int nn = t >> 3, jj = t & 7;
#pragma unroll
      for (int s = 0; s < 4; ++s) {
        int col8 = jj + s*8;
        u16x8 kv8 = *(const u16x8*)&KVb[((size_t)(b*4096 + n0 + nn))*256 + col8*8];
        float4 f0, f1;
        f0.x = bf2f(kv8[0]); f0.y = bf2f(kv8[1]); f0.z = bf2f(kv8[2]); f0.w = bf2f(kv8[3]);
        f1.x = bf2f(kv8[4]); f1.y = bf2f(kv8[5]); f1.z = bf2f(kv8[6]); f1.w = bf2f(kv8[7]);
        *(float4*)&KVs[nn*260 + col8*8] = f0;
        *(float4*)&KVs[nn*260 + col8*8 + 4] = f1;
      }
    }
    __syncthreads();
    float d0 = 0.f, d1 = 0.f;
    const float* kr = KVs + nl*260;
#pragma unroll 8
    for (int j4 = 0; j4 < 32; ++j4) {
      float4 kv = *(const float4*)(kr + j4*4);
      float4 qa = *(const float4*)(q0 + j4*4);
      float4 qb = *(const float4*)(q1 + j4*4);
      d0 += kv.x*qa.x + kv.y*qa.y + kv.z*qa.z + kv.w*qa.w;
      d1 += kv.x*qb.x + kv.y*qb.y + kv.z*qb.z + kv.w*qb.w;
    }
    int n = n0 + nl;
    float pmv = pm[(size_t)bk*4096 + n];
    float c = (den > 1e-6f) ? (pmv/(den + 1e-6f)) : 1.f;
    float vv = varArr[b*4096 + n];
    float al = c*rsqrtf(c*c*vv + 1e-5f);
    float dd0 = SCALE_*(al*d0 + qb0);
    float dd1 = SCALE_*(al*d1 + qb1);
    float mx = fmaxf(dd0, dd1);
    float e0 = expf(dd0 - mx), e1 = expf(dd1 - mx);
    float inv = 1.f/(e0 + e1);
    float o0 = e0*inv + 1e-8f;
    float o1 = e1*inv + 1e-8f;
    sA0 += o0; sA1 += o1;
    was[(p*2)*33 + nl] = o0*al;
    was[(p*2 + 1)*33 + nl] = o1*al;
    if (last) {
      outG[((size_t)(bk*2))*4096 + n] = o0*pmv;
      outG[((size_t)(bk*2 + 1))*4096 + n] = o1*pmv;
    }
    __syncthreads();
    const float* vb = KVs + 128 + dg*8;
    const float* wr = was + iu*33;
#pragma unroll 8
    for (int nn = 0; nn < 32; ++nn) {
      float wv = wr[nn];
      float4 v0 = *(const float4*)(vb + nn*260);
      float4 v1 = *(const float4*)(vb + nn*260 + 4);
      acc8[0] += wv*v0.x; acc8[1] += wv*v0.y; acc8[2] += wv*v0.z; acc8[3] += wv*v0.w;
      acc8[4] += wv*v1.x; acc8[5] += wv*v1.y; acc8[6] += wv*v1.z; acc8[7] += wv*v1.w;
    }
  }
#pragma unroll
  for (int m = 16; m >= 1; m >>= 1) {
    sA0 += __shfl_xor(sA0, m, 32);
    sA1 += __shfl_xor(sA1, m, 32);
  }
  if (nl == 0) {
    atomicAdd(&Ssum[bk*2], sA0);
    atomicAdd(&Ssum[bk*2 + 1], sA1);
  }
  float* up = Upart + ((size_t)(bi*16 + iu))*128 + dg*8;
  *(float4*)up = make_float4(acc8[0], acc8[1], acc8[2], acc8[3]);
  *(float4*)(up + 4) = make_float4(acc8[4], acc8[5], acc8[6], acc8[7]);
}

// ---- 5. GRU + MLP + next-iter q (MFMA); sums 32-chunk Upart ----
__global__ __launch_bounds__(256, 1) void gru_mlp_q_k(
    const float* __restrict__ Upart, const float* __restrict__ Ssum,
    const float* __restrict__ biasArr,
    const unsigned short* __restrict__ Wihbf, const unsigned short* __restrict__ Whhbf,
    const float* __restrict__ bih, const float* __restrict__ bhh,
    const float* __restrict__ mlp_g, const float* __restrict__ mlp_b,
    const unsigned short* __restrict__ W1bf, const float* __restrict__ b1,
    const unsigned short* __restrict__ Wm2bf, const float* __restrict__ b2,
    const float* __restrict__ ln_s_g, const float* __restrict__ ln_s_b,
    const unsigned short* __restrict__ Wqbf,
    float* __restrict__ slots, float* __restrict__ qg, float* __restrict__ qkb,
    float* __restrict__ SsumW, float* __restrict__ outObj, int last)
{
  __shared__ unsigned short FXx[2048], FXh[2048], Fhn[2048], Fsn[2048];
  __shared__ unsigned short Ft1[8192];
  __shared__ float G_rz[16*256];
  __shared__ float G_in[16*128];
  __shared__ float G_hn[16*128];
  __shared__ float hs_[16*128];
  __shared__ float os_[16*128];
  __shared__ float qkbL[16];

  int R0 = blockIdx.x*16;
  int t = threadIdx.x;
  int w = t >> 6, ln = t & 63;
  int lm = ln & 15, lq = ln >> 4;

  // ---- phase A: sum partials, build frags ----
  {
    int r = t >> 4, dseg = t & 15, ds8 = dseg*8;
    int R = R0 + r;
    float ua[8];
#pragma unroll
    for (int j = 0; j < 8; ++j) ua[j] = 0.f;
    const float* up = Upart + (size_t)R*128 + ds8;
#pragma unroll
    for (int ch = 0; ch < 32; ++ch) {
      float4 u0 = *(const float4*)(up + (size_t)ch*16384);
      float4 u1 = *(const float4*)(up + (size_t)ch*16384 + 4);
      ua[0]+=u0.x; ua[1]+=u0.y; ua[2]+=u0.z; ua[3]+=u0.w;
      ua[4]+=u1.x; ua[5]+=u1.y; ua[6]+=u1.z; ua[7]+=u1.w;
    }
    float Sv = 1.f/Ssum[R];
    float4 bv0 = *(const float4*)(biasArr + 128 + ds8);
    float4 bv1 = *(const float4*)(biasArr + 132 + ds8);
    float xv[8];
    xv[0]=ua[0]*Sv+bv0.x; xv[1]=ua[1]*Sv+bv0.y; xv[2]=ua[2]*Sv+bv0.z; xv[3]=ua[3]*Sv+bv0.w;
    xv[4]=ua[4]*Sv+bv1.x; xv[5]=ua[5]*Sv+bv1.y; xv[6]=ua[6]*Sv+bv1.z; xv[7]=ua[7]*Sv+bv1.w;
    float4 h0 = *(const float4*)(slots + (size_t)R*128 + ds8);
    float4 h1 = *(const float4*)(slots + (size_t)R*128 + ds8 + 4);
    *(float4*)(hs_ + r*128 + ds8) = h0;
    *(float4*)(hs_ + r*128 + ds8 + 4) = h1;
    int fa = ((dseg >> 2)*64 + (dseg & 3)*16 + r)*8;
    *(uint4*)&FXx[fa] = make_uint4(pack2(xv[0],xv[1]), pack2(xv[2],xv[3]),
                                   pack2(xv[4],xv[5]), pack2(xv[6],xv[7]));
    *(uint4*)&FXh[fa] = make_uint4(pack2(h0.x,h0.y), pack2(h0.z,h0.w),
                                   pack2(h1.x,h1.y), pack2(h1.z,h1.w));
    if (t < 16) qkbL[t] = 0.f;
  }
  __syncthreads();

  // ---- phase B: GRU gemms ----
  {
    bf16x8 ax[4], ah[4];
#pragma unroll
    for (int kc = 0; kc < 4; ++kc) {
      ax[kc] = *(const bf16x8*)(&FXx[(kc*64 + ln)*8]);
      ah[kc] = *(const bf16x8*)(&FXh[(kc*64 + ln)*8]);
    }
    if (w < 2) {
#pragma unroll
      for (int i = 0; i < 8; ++i) {
        int n0 = (w*8 + i)*16;
        f32x4 acc = f32x4{0.f,0.f,0.f,0.f};
#pragma unroll
        for (int kc = 0; kc < 4; ++kc) {
          bf16x8 bi_ = *(const bf16x8*)(&Wihbf[(size_t)(n0+lm)*128 + kc*32 + lq*8]);
          acc = __builtin_amdgcn_mfma_f32_16x16x32_bf16(ax[kc], bi_, acc, 0,0,0);
        }
#pragma unroll
        for (int kc = 0; kc < 4; ++kc) {
          bf16x8 bh_ = *(const bf16x8*)(&Whhbf[(size_t)(n0+lm)*128 + kc*32 + lq*8]);
          acc = __builtin_amdgcn_mfma_f32_16x16x32_bf16(ah[kc], bh_, acc, 0,0,0);
        }
#pragma unroll
        for (int reg = 0; reg < 4; ++reg)
          G_rz[(lq*4+reg)*256 + n0 + lm] = acc[reg];
      }
    } else if (w == 2) {
#pragma unroll
      for (int i = 0; i < 8; ++i) {
        int n0 = 256 + i*16;
        f32x4 acc = f32x4{0.f,0.f,0.f,0.f};
#pragma unroll
        for (int kc = 0; kc < 4; ++kc) {
          bf16x8 bi_ = *(const bf16x8*)(&Wihbf[(size_t)(n0+lm)*128 + kc*32 + lq*8]);
          acc = __builtin_amdgcn_mfma_f32_16x16x32_bf16(ax[kc], bi_, acc, 0,0,0);
        }
#pragma unroll
        for (int reg = 0; reg < 4; ++reg)
          G_in[(lq*4+reg)*128 + i*16 + lm] = acc[reg];
      }
    } else {
#pragma unroll
      for (int i = 0; i < 8; ++i) {
        int n0 = 256 + i*16;
        f32x4 acc = f32x4{0.f,0.f,0.f,0.f};
#pragma unroll
        for (int kc = 0; kc < 4; ++kc) {
          bf16x8 bh_ = *(const bf16x8*)(&Whhbf[(size_t)(n0+lm)*128 + kc*32 + lq*8]);
          acc = __builtin_amdgcn_mfma_f32_16x16x32_bf16(ah[kc], bh_, acc, 0,0,0);
        }
#pragma unroll
        for (int reg = 0; reg < 4; ++reg)
          G_hn[(lq*4+reg)*128 + i*16 + lm] = acc[reg];
      }
    }
  }
  __syncthreads();

  // ---- phase C: elementwise GRU + LN -> Fhn ----
  {
    int r = t >> 4, dseg = t & 15, ds8 = dseg*8;
    float hp[8];
    float s1 = 0.f, s2 = 0.f;
#pragma unroll
    for (int j = 0; j < 8; ++j) {
      int d = ds8 + j;
      float rg = G_rz[r*256 + d] + bih[d] + bhh[d];
      float zg = G_rz[r*256 + 128 + d] + bih[128+d] + bhh[128+d];
      float ing = G_in[r*128 + d] + bih[256+d];
      float hng = G_hn[r*128 + d] + bhh[256+d];
      float rv = 1.f/(1.f + expf(-rg));
      float zv = 1.f/(1.f + expf(-zg));
      float nv = tanhf(ing + rv*hng);
      float h0 = hs_[r*128 + d];
      float h = (1.f - zv)*nv + zv*h0;
      hp[j] = h;
      s1 += h; s2 += h*h;
    }
#pragma unroll
    for (int m = 8; m >= 1; m >>= 1) {
      s1 += __shfl_xor(s1, m, 16);
      s2 += __shfl_xor(s2, m, 16);
    }
    float mean = s1*(1.f/128.f);
    float var = s2*(1.f/128.f) - mean*mean;
    float rstd = rsqrtf(var + 1e-5f);
    float hv[8];
#pragma unroll
    for (int j = 0; j < 8; ++j) {
      int d = ds8 + j;
      hv[j] = (hp[j] - mean)*rstd*mlp_g[d] + mlp_b[d];
    }
    int fa = ((dseg >> 2)*64 + (dseg & 3)*16 + r)*8;
    *(uint4*)&Fhn[fa] = make_uint4(pack2(hv[0],hv[1]), pack2(hv[2],hv[3]),
                                   pack2(hv[4],hv[5]), pack2(hv[6],hv[7]));
  }
  __syncthreads();

  // ---- phase D: MLP1 + gelu -> Ft1 ----
  {
    bf16x8 af[4];
#pragma unroll
    for (int kc = 0; kc < 4; ++kc)
      af[kc] = *(const bf16x8*)(&Fhn[(kc*64 + ln)*8]);
#pragma unroll
    for (int i = 0; i < 8; ++i) {
      int n0 = (w*8 + i)*16;
      f32x4 acc = f32x4{0.f,0.f,0.f,0.f};
#pragma unroll
      for (int kc = 0; kc < 4; ++kc) {
        bf16x8 bw = *(const bf16x8*)(&W1bf[(size_t)(n0+lm)*128 + kc*32 + lq*8]);
        acc = __builtin_amdgcn_mfma_f32_16x16x32_bf16(af[kc], bw, acc, 0,0,0);
      }
      int kdim = n0 + lm;
      float bb = b1[kdim];
      int kc2 = kdim >> 5;
      int sub = (kdim >> 3) & 3;
      int jj = kdim & 7;
#pragma unroll
      for (int reg = 0; reg < 4; ++reg) {
        float v = acc[reg] + bb;
        float gel = 0.5f*v*(1.f + erff(v*0.70710678118654752f));
        Ft1[(kc2*64 + sub*16 + lq*4 + reg)*8 + jj] = f2bf(gel);
      }
    }
  }
  __syncthreads();

  // ---- phase E: MLP2 -> slots ----
  {
#pragma unroll
    for (int i = 0; i < 2; ++i) {
      int n0 = w*32 + i*16;
      f32x4 acc = f32x4{0.f,0.f,0.f,0.f};
#pragma unroll
      for (int kc = 0; kc < 16; ++kc) {
        bf16x8 af = *(const bf16x8*)(&Ft1[(kc*64 + ln)*8]);
        bf16x8 bw = *(const bf16x8*)(&Wm2bf[(size_t)(n0+lm)*512 + kc*32 + lq*8]);
        acc = __builtin_amdgcn_mfma_f32_16x16x32_bf16(af, bw, acc, 0,0,0);
      }
      int n = n0 + lm;
      float bb = b2[n];
#pragma unroll
      for (int reg = 0; reg < 4; ++reg) {
        int row = lq*4 + reg;
        float o = acc[reg] + bb;
        slots[(size_t)(R0 + row)*128 + n] = o;
        os_[row*128 + n] = o;
        if (last) outObj[(size_t)(R0 + row)*128 + n] = o;
      }
    }
  }

  if (last) return;

  __syncthreads();
  // ---- phase F1: LN(slots) -> Fsn ----
  {
    int r = t >> 4, dseg = t & 15, ds8 = dseg*8;
    float ov[8];
    float s1 = 0.f, s2 = 0.f;
#pragma unroll
    for (int j = 0; j < 8; ++j) {
      float o = os_[r*128 + ds8 + j];
      ov[j] = o; s1 += o; s2 += o*o;
    }
#pragma unroll
    for (int m = 8; m >= 1; m >>= 1) {
      s1 += __shfl_xor(s1, m, 16);
      s2 += __shfl_xor(s2, m, 16);
    }
    float mean = s1*(1.f/128.f);
    float var = s2*(1.f/128.f) - mean*mean;
    float rstd = rsqrtf(var + 1e-5f);
    float sv[8];
#pragma unroll
    for (int j = 0; j < 8; ++j) {
      int d = ds8 + j;
      sv[j] = (ov[j] - mean)*rstd*ln_s_g[d] + ln_s_b[d];
    }
    int fa = ((dseg >> 2)*64 + (dseg & 3)*16 + r)*8;
    *(uint4*)&Fsn[fa] = make_uint4(pack2(sv[0],sv[1]), pack2(sv[2],sv[3]),
                                   pack2(sv[4],sv[5]), pack2(sv[6],sv[7]));
  }
  __syncthreads();

  // ---- phase F2: q + qkb ----
  {
    bf16x8 af[4];
#pragma unroll
    for (int kc = 0; kc < 4; ++kc)
      af[kc] = *(const bf16x8*)(&Fsn[(kc*64 + ln)*8]);
    float pr[4] = {0.f, 0.f, 0.f, 0.f};
#pragma unroll
    for (int i = 0; i < 2; ++i) {
      int n0 = w*32 + i*16;
      f32x4 acc = f32x4{0.f,0.f,0.f,0.f};
#pragma unroll
      for (int kc = 0; kc < 4; ++kc) {
        bf16x8 bw = *(const bf16x8*)(&Wqbf[(size_t)(n0+lm)*128 + kc*32 + lq*8]);
        acc = __builtin_amdgcn_mfma_f32_16x16x32_bf16(af[kc], bw, acc, 0,0,0);
      }
      int n = n0 + lm;
      float bk_ = biasArr[n];
#pragma unroll
      for (int reg = 0; reg < 4; ++reg) {
        int row = lq*4 + reg;
        qg[(size_t)(R0 + row)*128 + n] = acc[reg];
        pr[reg] += acc[reg]*bk_;
      }
    }
#pragma unroll
    for (int reg = 0; reg < 4; ++reg) {
#pragma unroll
      for (int m = 8; m >= 1; m >>= 1) pr[reg] += __shfl_xor(pr[reg], m, 16);
    }
    if (lm == 0) {
#pragma unroll
      for (int reg = 0; reg < 4; ++reg)
        atomicAdd(&qkbL[lq*4 + reg], pr[reg]);
    }
  }
  __syncthreads();
  if (t < 16) {
    qkb[R0 + t] = qkbL[t];
    SsumW[R0 + t] = 0.f;
  }
}

extern "C" void kernel_launch(void* const* d_in, const int* in_sizes, int n_in,
                              void* d_out, int out_size, void* d_ws, size_t ws_size,
                              hipStream_t stream) {
  const float* tokens = (const float*)d_in[0];
  const float* pslots = (const float*)d_in[1];
  const float* pmasks = (const float*)d_in[2];
  const float* eps    = (const float*)d_in[3];
  const float* ln_in_g= (const float*)d_in[4];
  const float* ln_in_b= (const float*)d_in[5];
  const float* ln_s_g = (const float*)d_in[6];
  const float* ln_s_b = (const float*)d_in[7];
  const float* Wq     = (const float*)d_in[8];
  const float* Wk     = (const float*)d_in[9];
  const float* Wv     = (const float*)d_in[10];
  const float* Wih    = (const float*)d_in[11];
  const float* Whh    = (const float*)d_in[12];
  const float* bih    = (const float*)d_in[13];
  const float* bhh    = (const float*)d_in[14];
  const float* mlp_g  = (const float*)d_in[15];
  const float* mlp_b  = (const float*)d_in[16];
  const float* W1     = (const float*)d_in[17];
  const float* b1     = (const float*)d_in[18];
  const float* W2     = (const float*)d_in[19];
  const float* b2     = (const float*)d_in[20];
  float* ws  = (float*)d_ws;
  float* out = (float*)d_out;
  unsigned short* wkvbf = (unsigned short*)(ws + OFF_WKVBF);
  unsigned short* wqbf  = (unsigned short*)(ws + OFF_WQBF);
  unsigned short* wihbf = (unsigned short*)(ws + OFF_WIHBF);
  unsigned short* whhbf = (unsigned short*)(ws + OFF_WHHBF);
  unsigned short* w1bf  = (unsigned short*)(ws + OFF_W1BF);
  unsigned short* wm2bf = (unsigned short*)(ws + OFF_WM2BF);
  unsigned short* kvb   = (unsigned short*)(ws + OFF_KVB);

  prep_all_k<<<1088, 256, 0, stream>>>(Wk, Wv, ln_in_g, ln_in_b,
                                       Wq, Wih, Whh, W1, W2, pmasks,
                                       wkvbf, ws + OFF_GSUM, ws + OFF_BIAS,
                                       wqbf, wihbf, whhbf, w1bf, wm2bf,
                                       ws + OFF_DENOM);
  gemm_kv_k<<<512, 256, 0, stream>>>(tokens, wkvbf, ws + OFF_GSUM,
                                     kvb, ws + OFF_VAR);
  slots_init_q_k<<<8, 256, 0, stream>>>(pslots, eps, ln_s_g, ln_s_b,
                                        wqbf, ws + OFF_BIAS,
                                        ws + OFF_SLOTS, ws + OFF_Q,
                                        ws + OFF_QKB, ws + OFF_SSUM);
  for (int it = 0; it < 3; ++it) {
    int last = (it == 2);
    attn_fused_k<<<256, 256, 0, stream>>>(kvb, ws + OFF_Q, ws + OFF_QKB,
                                          ws + OFF_VAR, ws + OFF_DENOM, pmasks,
                                          ws + OFF_UPART, ws + OFF_SSUM,
                                          out + 16384, last);
    gru_mlp_q_k<<<8, 256, 0, stream>>>(ws + OFF_UPART, ws + OFF_SSUM,
                                       ws + OFF_BIAS, wihbf, whhbf, bih, bhh,
                                       mlp_g, mlp_b, w1bf, b1, wm2bf, b2,
                                       ln_s_g, ln_s_b, wqbf,
                                       ws + OFF_SLOTS, ws + OFF_Q, ws + OFF_QKB,
                                       ws + OFF_SSUM, out, last);
  }
}

// Round 6
// 376.484 us; speedup vs baseline: 1.0565x; 1.0102x over previous
//
#include <hip/hip_runtime.h>
#include <math.h>

#define SCALE_ 0.08838834764831843f

typedef __attribute__((ext_vector_type(8))) short bf16x8;
typedef __attribute__((ext_vector_type(4))) float f32x4;

// ---- workspace layout (float offsets), total ~5.53M floats = 22 MB ----
static const size_t OFF_VAR   = 0;        // 32768
static const size_t OFF_DENOM = 32768;    // 64
static const size_t OFF_GSUM  = 32832;    // 256
static const size_t OFF_BIAS  = 33088;    // 256
static const size_t OFF_QKB   = 33344;    // 128
static const size_t OFF_SSUM  = 33472;    // 128
static const size_t OFF_SLOTS = 33600;    // 16384
static const size_t OFF_Q     = 49984;    // 16384
static const size_t OFF_WQBF  = 66368;    // 8192 fl Wq[128][128] bf16
static const size_t OFF_WIHBF = 74560;    // 24576 fl Wih[384][128] bf16
static const size_t OFF_WHHBF = 99136;    // 24576 fl Whh[384][128] bf16
static const size_t OFF_W1BF  = 123712;   // 32768 fl W1[512][128] bf16
static const size_t OFF_WM2BF = 156480;   // 32768 fl W2[128][512] bf16
static const size_t OFF_WKVBF = 189248;   // 98304 fl (196608 bf16) [256][768]
static const size_t OFF_UPART = 287552;   // 1048576 fl [8][64][16][128]
static const size_t OFF_KB    = 1336128;  // 2097152 fl (4194304 bf16) [b][n][128]
static const size_t OFF_VT    = 3433280;  // 2097152 fl (4194304 bf16) [b][128][4096]

__device__ __forceinline__ float wred64(float v) {
#pragma unroll
  for (int off = 32; off > 0; off >>= 1) v += __shfl_xor(v, off, 64);
  return v;
}

__device__ __forceinline__ unsigned short f2bf(float f) {
  unsigned u = __float_as_uint(f);
  unsigned r = (u + 0x7fffu + ((u >> 16) & 1u)) >> 16;
  return (unsigned short)r;
}

__device__ __forceinline__ unsigned pack2(float a, float b) {
  return (unsigned)f2bf(a) | ((unsigned)f2bf(b) << 16);
}

// ---- 1. merged prep ----
__global__ __launch_bounds__(256) void prep_all_k(
    const float* __restrict__ Wk, const float* __restrict__ Wv,
    const float* __restrict__ g, const float* __restrict__ bb,
    const float* __restrict__ Wq, const float* __restrict__ Wih,
    const float* __restrict__ Whh, const float* __restrict__ W1,
    const float* __restrict__ W2, const float* __restrict__ pm,
    unsigned short* __restrict__ wkv, float* __restrict__ gsum,
    float* __restrict__ biasArr,
    unsigned short* __restrict__ Wqbf, unsigned short* __restrict__ Wihbf,
    unsigned short* __restrict__ Whhbf, unsigned short* __restrict__ W1bf,
    unsigned short* __restrict__ Wm2bf, float* __restrict__ denomArr)
{
  __shared__ float red4[4];
  int bi = blockIdx.x, t = threadIdx.x;
  if (bi < 64) {
    int j = bi*4 + (t >> 6), lane = t & 63;
    const float* w = (j < 128) ? (Wk + (size_t)j*768) : (Wv + (size_t)(j-128)*768);
    float gs = 0.f, bs = 0.f;
#pragma unroll
    for (int s = 0; s < 12; ++s) {
      int dd = lane + s*64;
      float wv = w[dd], gv = g[dd];
      gs += gv*wv; bs += bb[dd]*wv;
      wkv[(size_t)j*768 + dd] = f2bf(wv*gv);
    }
    gs = wred64(gs); bs = wred64(bs);
    if (lane == 0) { gsum[j] = gs; biasArr[j] = bs; }
  } else if (bi < 128) {
    int idx = (bi-64)*256 + t;  Wqbf[idx]  = f2bf(Wq[idx]);
  } else if (bi < 320) {
    int idx = (bi-128)*256 + t; Wihbf[idx] = f2bf(Wih[idx]);
  } else if (bi < 512) {
    int idx = (bi-320)*256 + t; Whhbf[idx] = f2bf(Whh[idx]);
  } else if (bi < 768) {
    int idx = (bi-512)*256 + t; W1bf[idx]  = f2bf(W1[idx]);
  } else if (bi < 1024) {
    int idx = (bi-768)*256 + t; Wm2bf[idx] = f2bf(W2[idx]);
  } else {
    int bk = bi - 1024;
    float s = 0.f;
#pragma unroll
    for (int k = 0; k < 16; ++k) s += pm[bk*4096 + t + k*256];
    s = wred64(s);
    if ((t & 63) == 0) red4[t >> 6] = s;
    __syncthreads();
    if (t == 0) denomArr[bk] = (red4[0]+red4[1]+red4[2]+red4[3])*(1.f/4096.f);
  }
}

// ---- 2. streaming MFMA GEMM (no LDS, no barriers) ----
// grid 512 x 256: block = 64 rows x 256 cols; wave = 32 rows x 128 cols.
// B-frags (wkv [256][768] bf16) loaded directly from L2 as 16B bf16x8.
// Outputs: Kb bf16 [b][n][128] (K) and VT bf16 [b][128][4096] (V transposed).
__global__ __launch_bounds__(256) void gemm_kv_k(
    const float* __restrict__ tokens, const unsigned short* __restrict__ wkv,
    const float* __restrict__ gsum, unsigned short* __restrict__ Kb,
    unsigned short* __restrict__ VT, float* __restrict__ varArr)
{
  int bi = blockIdx.x;
  int r0 = bi*64;
  int t = threadIdx.x;
  int w = t >> 6, ln = t & 63;
  int lm = ln & 15, lq = ln >> 4;
  int rowbase = r0 + (w >> 1)*32;
  int colbase = (w & 1)*128;

  const float* a0p = tokens + (size_t)(rowbase + lm)*768 + lq*8;
  const float* a1p = tokens + (size_t)(rowbase + 16 + lm)*768 + lq*8;
  const unsigned short* bp = wkv + (size_t)(colbase + lm)*768 + lq*8;

  f32x4 acc[2][8];
#pragma unroll
  for (int a = 0; a < 2; ++a)
#pragma unroll
    for (int c = 0; c < 8; ++c) acc[a][c] = f32x4{0.f, 0.f, 0.f, 0.f};
  float s1a = 0.f, s2a = 0.f, s1b = 0.f, s2b = 0.f;

  // prologue: load k=0
  float4 cA0a = *(const float4*)(a0p);
  float4 cA0b = *(const float4*)(a0p + 4);
  float4 cA1a = *(const float4*)(a1p);
  float4 cA1b = *(const float4*)(a1p + 4);
  bf16x8 Bf[2][8];
#pragma unroll
  for (int nt = 0; nt < 8; ++nt)
    Bf[0][nt] = *(const bf16x8*)(bp + (size_t)(nt*16)*768);

#pragma unroll 2
  for (int k = 0; k < 24; ++k) {
    const int kb = k & 1;
    float4 nA0a, nA0b, nA1a, nA1b;
    if (k < 23) {
      const float* a0n = a0p + (k+1)*32;
      const float* a1n = a1p + (k+1)*32;
      nA0a = *(const float4*)(a0n);
      nA0b = *(const float4*)(a0n + 4);
      nA1a = *(const float4*)(a1n);
      nA1b = *(const float4*)(a1n + 4);
#pragma unroll
      for (int nt = 0; nt < 8; ++nt)
        Bf[kb ^ 1][nt] = *(const bf16x8*)(bp + (size_t)(nt*16)*768 + (k+1)*32);
    }
    // stats + pack current A
    s1a += cA0a.x + cA0a.y + cA0a.z + cA0a.w + cA0b.x + cA0b.y + cA0b.z + cA0b.w;
    s2a += cA0a.x*cA0a.x + cA0a.y*cA0a.y + cA0a.z*cA0a.z + cA0a.w*cA0a.w
         + cA0b.x*cA0b.x + cA0b.y*cA0b.y + cA0b.z*cA0b.z + cA0b.w*cA0b.w;
    s1b += cA1a.x + cA1a.y + cA1a.z + cA1a.w + cA1b.x + cA1b.y + cA1b.z + cA1b.w;
    s2b += cA1a.x*cA1a.x + cA1a.y*cA1a.y + cA1a.z*cA1a.z + cA1a.w*cA1a.w
         + cA1b.x*cA1b.x + cA1b.y*cA1b.y + cA1b.z*cA1b.z + cA1b.w*cA1b.w;
    bf16x8 af0, af1;
    { uint4 tmp = make_uint4(pack2(cA0a.x, cA0a.y), pack2(cA0a.z, cA0a.w),
                             pack2(cA0b.x, cA0b.y), pack2(cA0b.z, cA0b.w));
      af0 = *(bf16x8*)&tmp; }
    { uint4 tmp = make_uint4(pack2(cA1a.x, cA1a.y), pack2(cA1a.z, cA1a.w),
                             pack2(cA1b.x, cA1b.y), pack2(cA1b.z, cA1b.w));
      af1 = *(bf16x8*)&tmp; }
#pragma unroll
    for (int nt = 0; nt < 8; ++nt) {
      acc[0][nt] = __builtin_amdgcn_mfma_f32_16x16x32_bf16(af0, Bf[kb][nt], acc[0][nt], 0, 0, 0);
      acc[1][nt] = __builtin_amdgcn_mfma_f32_16x16x32_bf16(af1, Bf[kb][nt], acc[1][nt], 0, 0, 0);
    }
    cA0a = nA0a; cA0b = nA0b; cA1a = nA1a; cA1b = nA1b;
  }

  // stats: reduce over lq (xor bits 4,5)
  s1a += __shfl_xor(s1a, 16, 64); s1a += __shfl_xor(s1a, 32, 64);
  s2a += __shfl_xor(s2a, 16, 64); s2a += __shfl_xor(s2a, 32, 64);
  s1b += __shfl_xor(s1b, 16, 64); s1b += __shfl_xor(s1b, 32, 64);
  s2b += __shfl_xor(s2b, 16, 64); s2b += __shfl_xor(s2b, 32, 64);
  float mean0 = s1a*(1.f/768.f), var0 = s2a*(1.f/768.f) - mean0*mean0;
  float mean1 = s1b*(1.f/768.f), var1 = s2b*(1.f/768.f) - mean1*mean1;
  if ((w & 1) == 0 && lq == 0) {
    varArr[rowbase + lm] = var0;
    varArr[rowbase + 16 + lm] = var1;
  }
  float m0R[4], m1R[4];
#pragma unroll
  for (int reg = 0; reg < 4; ++reg) {
    m0R[reg] = __shfl(mean0, lq*4 + reg, 64);
    m1R[reg] = __shfl(mean1, lq*4 + reg, 64);
  }

  if ((w & 1) == 0) {
    // K: cols 0..127 -> Kb[tok][col]
#pragma unroll
    for (int nt = 0; nt < 8; ++nt) {
      int col = nt*16 + lm;
      float gs = gsum[col];
#pragma unroll
      for (int T = 0; T < 2; ++T) {
#pragma unroll
        for (int reg = 0; reg < 4; ++reg) {
          int tok = rowbase + T*16 + lq*4 + reg;
          float mv = T ? m1R[reg] : m0R[reg];
          Kb[(size_t)tok*128 + col] = f2bf(acc[T][nt][reg] - mv*gs);
        }
      }
    }
  } else {
    // V: cols 128..255 -> VT[b][d][n], 4 consecutive n packed per lane
#pragma unroll
    for (int nt = 0; nt < 8; ++nt) {
      int d = nt*16 + lm;
      float gs = gsum[128 + d];
#pragma unroll
      for (int T = 0; T < 2; ++T) {
        int tok0 = rowbase + T*16 + lq*4;
        int b = tok0 >> 12;
        int n = tok0 & 4095;
        float m0 = T ? m1R[0] : m0R[0];
        float m1 = T ? m1R[1] : m0R[1];
        float m2 = T ? m1R[2] : m0R[2];
        float m3 = T ? m1R[3] : m0R[3];
        ushort4 v;
        v.x = f2bf(acc[T][nt][0] - m0*gs);
        v.y = f2bf(acc[T][nt][1] - m1*gs);
        v.z = f2bf(acc[T][nt][2] - m2*gs);
        v.w = f2bf(acc[T][nt][3] - m3*gs);
        *(ushort4*)&VT[((size_t)(b*128 + d))*4096 + n] = v;
      }
    }
  }
}

// ---- 3. slots init + LN + q (iter 0), MFMA; zeroes Ssum ----
__global__ __launch_bounds__(256, 1) void slots_init_q_k(
    const float* __restrict__ ps, const float* __restrict__ eps,
    const float* __restrict__ g_s, const float* __restrict__ b_s,
    const unsigned short* __restrict__ Wqbf, const float* __restrict__ biasArr,
    float* __restrict__ slots, float* __restrict__ qg, float* __restrict__ qkb,
    float* __restrict__ Ssum)
{
  __shared__ unsigned short Fsn[2048];
  __shared__ float qkbL[16];
  int R0 = blockIdx.x*16;
  int t = threadIdx.x;
  int w = t >> 6, ln = t & 63, lm = ln & 15, lq = ln >> 4;
  if (t < 16) qkbL[t] = 0.f;
  {
    int r = t >> 4, dseg = t & 15, ds8 = dseg*8;
    int row = R0 + r, bk = row >> 1;
    float xv[8]; float s1 = 0.f, s2 = 0.f;
#pragma unroll
    for (int j = 0; j < 8; ++j) {
      int d = ds8 + j;
      float x = ps[bk*128 + d] + 0.01f*eps[row*128 + d];
      slots[row*128 + d] = x;
      xv[j] = x; s1 += x; s2 += x*x;
    }
#pragma unroll
    for (int m = 8; m >= 1; m >>= 1) {
      s1 += __shfl_xor(s1, m, 16);
      s2 += __shfl_xor(s2, m, 16);
    }
    float mean = s1*(1.f/128.f);
    float var = s2*(1.f/128.f) - mean*mean;
    float rstd = rsqrtf(var + 1e-5f);
    float sv[8];
#pragma unroll
    for (int j = 0; j < 8; ++j) {
      int d = ds8 + j;
      sv[j] = (xv[j] - mean)*rstd*g_s[d] + b_s[d];
    }
    int fa = ((dseg >> 2)*64 + (dseg & 3)*16 + r)*8;
    *(uint4*)&Fsn[fa] = make_uint4(pack2(sv[0],sv[1]), pack2(sv[2],sv[3]),
                                   pack2(sv[4],sv[5]), pack2(sv[6],sv[7]));
  }
  __syncthreads();
  {
    bf16x8 af[4];
#pragma unroll
    for (int kc = 0; kc < 4; ++kc)
      af[kc] = *(const bf16x8*)(&Fsn[(kc*64 + ln)*8]);
    float pr[4] = {0.f, 0.f, 0.f, 0.f};
#pragma unroll
    for (int i = 0; i < 2; ++i) {
      int n0 = w*32 + i*16;
      f32x4 acc = f32x4{0.f,0.f,0.f,0.f};
#pragma unroll
      for (int kc = 0; kc < 4; ++kc) {
        bf16x8 bw = *(const bf16x8*)(&Wqbf[(size_t)(n0+lm)*128 + kc*32 + lq*8]);
        acc = __builtin_amdgcn_mfma_f32_16x16x32_bf16(af[kc], bw, acc, 0,0,0);
      }
      int n = n0 + lm;
      float bk_ = biasArr[n];
#pragma unroll
      for (int reg = 0; reg < 4; ++reg) {
        int row = lq*4 + reg;
        qg[(size_t)(R0 + row)*128 + n] = acc[reg];
        pr[reg] += acc[reg]*bk_;
      }
    }
#pragma unroll
    for (int reg = 0; reg < 4; ++reg) {
#pragma unroll
      for (int m = 8; m >= 1; m >>= 1) pr[reg] += __shfl_xor(pr[reg], m, 16);
    }
    if (lm == 0) {
#pragma unroll
      for (int reg = 0; reg < 4; ++reg)
        atomicAdd(&qkbL[lq*4 + reg], pr[reg]);
    }
  }
  __syncthreads();
  if (t < 16) { qkb[R0 + t] = qkbL[t]; Ssum[R0 + t] = 0.f; }
}

// ---- 4. MFMA fused attention ----
// grid 256 x 128: b = bi>>5, nch = bi&31; wave covers 64 tokens.
// dots^T[q][tok] = Q (A-frag, from qg) x K (B-frag, direct L2 from Kb).
// softmax within-lane (query pairs in adjacent acc regs); P -> small LDS;
// PV: P (A-frag from LDS) x VT (B-frag direct L2). U per-wave global partials.
__global__ __launch_bounds__(128) void attn_fused_k(
    const unsigned short* __restrict__ Kb, const unsigned short* __restrict__ VT,
    const float* __restrict__ qg, const float* __restrict__ qkb,
    const float* __restrict__ varArr, const float* __restrict__ denomArr,
    const float* __restrict__ pm,
    float* __restrict__ Upart, float* __restrict__ Ssum,
    float* __restrict__ outG, int last)
{
  __shared__ unsigned short Pl[2][16*68];
  int bi = blockIdx.x;
  int b = bi >> 5, nch = bi & 31;
  int t = threadIdx.x;
  int wv = t >> 6, ln = t & 63;
  int lm = ln & 15, lq = ln >> 4;
  int ntok0 = nch*128 + wv*64;
  unsigned short* pl = &Pl[wv][0];

  // Q fragments (q = lm, k = kc*32 + lq*8 + j)
  bf16x8 qf[4];
#pragma unroll
  for (int kc = 0; kc < 4; ++kc) {
    const float* qp = qg + (size_t)(b*16 + lm)*128 + kc*32 + lq*8;
    float4 q0 = *(const float4*)qp;
    float4 q1 = *(const float4*)(qp + 4);
    uint4 tmp = make_uint4(pack2(q0.x,q0.y), pack2(q0.z,q0.w),
                           pack2(q1.x,q1.y), pack2(q1.z,q1.w));
    qf[kc] = *(bf16x8*)&tmp;
  }
  float qkbv[4];
#pragma unroll
  for (int reg = 0; reg < 4; ++reg) qkbv[reg] = qkb[b*16 + lq*4 + reg];
  float den0 = denomArr[b*8 + lq*2];
  float den1 = denomArr[b*8 + lq*2 + 1];
  bool g0 = den0 > 1e-6f, g1 = den1 > 1e-6f;
  float inv0 = 1.f/(den0 + 1e-6f), inv1 = 1.f/(den1 + 1e-6f);

  f32x4 Uacc[8];
#pragma unroll
  for (int dt = 0; dt < 8; ++dt) Uacc[dt] = f32x4{0.f,0.f,0.f,0.f};
  float sAcc[4] = {0.f, 0.f, 0.f, 0.f};

#pragma unroll
  for (int half = 0; half < 2; ++half) {
    int tk0 = ntok0 + half*32;
#pragma unroll
    for (int ti = 0; ti < 2; ++ti) {
      int n0 = tk0 + ti*16;
      int n = n0 + lm;
      f32x4 dacc = f32x4{0.f,0.f,0.f,0.f};
      const unsigned short* kp = Kb + ((size_t)(b*4096 + n))*128 + lq*8;
#pragma unroll
      for (int kc = 0; kc < 4; ++kc) {
        bf16x8 kf = *(const bf16x8*)(kp + kc*32);
        dacc = __builtin_amdgcn_mfma_f32_16x16x32_bf16(qf[kc], kf, dacc, 0,0,0);
      }
      float vv = varArr[b*4096 + n];
      float pm0 = pm[((size_t)(b*8 + lq*2))*4096 + n];
      float pm1 = pm[((size_t)(b*8 + lq*2 + 1))*4096 + n];
      float c0 = g0 ? pm0*inv0 : 1.f;
      float c1 = g1 ? pm1*inv1 : 1.f;
      float al0 = c0*rsqrtf(c0*c0*vv + 1e-5f);
      float al1 = c1*rsqrtf(c1*c1*vv + 1e-5f);
      float dd0 = SCALE_*(al0*dacc[0] + qkbv[0]);
      float dd1 = SCALE_*(al0*dacc[1] + qkbv[1]);
      float mx0 = fmaxf(dd0, dd1);
      float e0 = expf(dd0 - mx0), e1 = expf(dd1 - mx0);
      float is0 = 1.f/(e0 + e1);
      float o0 = e0*is0 + 1e-8f, o1 = e1*is0 + 1e-8f;
      float dd2 = SCALE_*(al1*dacc[2] + qkbv[2]);
      float dd3 = SCALE_*(al1*dacc[3] + qkbv[3]);
      float mx1 = fmaxf(dd2, dd3);
      float e2 = expf(dd2 - mx1), e3 = expf(dd3 - mx1);
      float is1 = 1.f/(e2 + e3);
      float o2 = e2*is1 + 1e-8f, o3 = e3*is1 + 1e-8f;
      sAcc[0] += o0; sAcc[1] += o1; sAcc[2] += o2; sAcc[3] += o3;
      if (last) {
        size_t ob = ((size_t)(b*16 + lq*4))*4096 + n;
        outG[ob]          = o0*pm0;
        outG[ob + 4096]   = o1*pm0;
        outG[ob + 8192]   = o2*pm1;
        outG[ob + 12288]  = o3*pm1;
      }
      int pc = half*32 + ti*16 + lm;
      pl[(lq*4 + 0)*68 + pc] = f2bf(o0*al0);
      pl[(lq*4 + 1)*68 + pc] = f2bf(o1*al0);
      pl[(lq*4 + 2)*68 + pc] = f2bf(o2*al1);
      pl[(lq*4 + 3)*68 + pc] = f2bf(o3*al1);
    }
    // PV over this 32-token chunk (same-wave LDS write->read, no barrier)
    bf16x8 pf = *(const bf16x8*)&pl[lm*68 + half*32 + lq*8];
    const unsigned short* vp = VT + ((size_t)(b*128 + lm))*4096 + tk0 + lq*8;
#pragma unroll
    for (int dt = 0; dt < 8; ++dt) {
      bf16x8 vf = *(const bf16x8*)(vp + (size_t)(dt*16)*4096);
      Uacc[dt] = __builtin_amdgcn_mfma_f32_16x16x32_bf16(pf, vf, Uacc[dt], 0,0,0);
    }
  }

  // Ssum: reduce over lm then atomic
#pragma unroll
  for (int reg = 0; reg < 4; ++reg) {
    float r = sAcc[reg];
    r += __shfl_xor(r, 1, 64); r += __shfl_xor(r, 2, 64);
    r += __shfl_xor(r, 4, 64); r += __shfl_xor(r, 8, 64);
    if (lm == 0) atomicAdd(&Ssum[b*16 + lq*4 + reg], r);
  }
  // U partial: Upart[b][nch*2+wv][q][d]
  float* up = Upart + ((size_t)(b*64 + nch*2 + wv))*2048;
#pragma unroll
  for (int dt = 0; dt < 8; ++dt)
#pragma unroll
    for (int reg = 0; reg < 4; ++reg)
      up[(lq*4 + reg)*128 + dt*16 + lm] = Uacc[dt][reg];
}

// ---- 5. GRU + MLP + next-iter q (MFMA); sums 64-chunk Upart ----
__global__ __launch_bounds__(256, 1) void gru_mlp_q_k(
    const float* __restrict__ Upart, const float* __restrict__ Ssum,
    const float* __restrict__ biasArr,
    const unsigned short* __restrict__ Wihbf, const unsigned short* __restrict__ Whhbf,
    const float* __restrict__ bih, const float* __restrict__ bhh,
    const float* __restrict__ mlp_g, const float* __restrict__ mlp_b,
    const unsigned short* __restrict__ W1bf, const float* __restrict__ b1,
    const unsigned short* __restrict__ Wm2bf, const float* __restrict__ b2,
    const float* __restrict__ ln_s_g, const float* __restrict__ ln_s_b,
    const unsigned short* __restrict__ Wqbf,
    float* __restrict__ slots, float* __restrict__ qg, float* __restrict__ qkb,
    float* __restrict__ SsumW, float* __restrict__ outObj, int last)
{
  __shared__ unsigned short FXx[2048], FXh[2048], Fhn[2048], Fsn[2048];
  __shared__ unsigned short Ft1[8192];
  __shared__ float G_rz[16*256];
  __shared__ float G_in[16*128];
  __shared__ float G_hn[16*128];
  __shared__ float hs_[16*128];
  __shared__ float os_[16*128];
  __shared__ float qkbL[16];

  int R0 = blockIdx.x*16;
  int t = threadIdx.x;
  int w = t >> 6, ln = t & 63;
  int lm = ln & 15, lq = ln >> 4;

  // ---- phase A: sum 64 partials, build frags ----
  {
    int r = t >> 4, dseg = t & 15, ds8 = dseg*8;
    int R = R0 + r;
    float ua[8];
#pragma unroll
    for (int j = 0; j < 8; ++j) ua[j] = 0.f;
    const float* up = Upart + (size_t)blockIdx.x*131072 + r*128 + ds8;
#pragma unroll 8
    for (int ch = 0; ch < 64; ++ch) {
      float4 u0 = *(const float4*)(up + (size_t)ch*2048);
      float4 u1 = *(const float4*)(up + (size_t)ch*2048 + 4);
      ua[0]+=u0.x; ua[1]+=u0.y; ua[2]+=u0.z; ua[3]+=u0.w;
      ua[4]+=u1.x; ua[5]+=u1.y; ua[6]+=u1.z; ua[7]+=u1.w;
    }
    float Sv = 1.f/Ssum[R];
    float4 bv0 = *(const float4*)(biasArr + 128 + ds8);
    float4 bv1 = *(const float4*)(biasArr + 132 + ds8);
    float xv[8];
    xv[0]=ua[0]*Sv+bv0.x; xv[1]=ua[1]*Sv+bv0.y; xv[2]=ua[2]*Sv+bv0.z; xv[3]=ua[3]*Sv+bv0.w;
    xv[4]=ua[4]*Sv+bv1.x; xv[5]=ua[5]*Sv+bv1.y; xv[6]=ua[6]*Sv+bv1.z; xv[7]=ua[7]*Sv+bv1.w;
    float4 h0 = *(const float4*)(slots + (size_t)R*128 + ds8);
    float4 h1 = *(const float4*)(slots + (size_t)R*128 + ds8 + 4);
    *(float4*)(hs_ + r*128 + ds8) = h0;
    *(float4*)(hs_ + r*128 + ds8 + 4) = h1;
    int fa = ((dseg >> 2)*64 + (dseg & 3)*16 + r)*8;
    *(uint4*)&FXx[fa] = make_uint4(pack2(xv[0],xv[1]), pack2(xv[2],xv[3]),
                                   pack2(xv[4],xv[5]), pack2(xv[6],xv[7]));
    *(uint4*)&FXh[fa] = make_uint4(pack2(h0.x,h0.y), pack2(h0.z,h0.w),
                                   pack2(h1.x,h1.y), pack2(h1.z,h1.w));
    if (t < 16) qkbL[t] = 0.f;
  }
  __syncthreads();

  // ---- phase B: GRU gemms ----
  {
    bf16x8 ax[4], ah[4];
#pragma unroll
    for (int kc = 0; kc < 4; ++kc) {
      ax[kc] = *(const bf16x8*)(&FXx[(kc*64 + ln)*8]);
      ah[kc] = *(const bf16x8*)(&FXh[(kc*64 + ln)*8]);
    }
    if (w < 2) {
#pragma unroll
      for (int i = 0; i < 8; ++i) {
        int n0 = (w*8 + i)*16;
        f32x4 acc = f32x4{0.f,0.f,0.f,0.f};
#pragma unroll
        for (int kc = 0; kc < 4; ++kc) {
          bf16x8 bi_ = *(const bf16x8*)(&Wihbf[(size_t)(n0+lm)*128 + kc*32 + lq*8]);
          acc = __builtin_amdgcn_mfma_f32_16x16x32_bf16(ax[kc], bi_, acc, 0,0,0);
        }
#pragma unroll
        for (int kc = 0; kc < 4; ++kc) {
          bf16x8 bh_ = *(const bf16x8*)(&Whhbf[(size_t)(n0+lm)*128 + kc*32 + lq*8]);
          acc = __builtin_amdgcn_mfma_f32_16x16x32_bf16(ah[kc], bh_, acc, 0,0,0);
        }
#pragma unroll
        for (int reg = 0; reg < 4; ++reg)
          G_rz[(lq*4+reg)*256 + n0 + lm] = acc[reg];
      }
    } else if (w == 2) {
#pragma unroll
      for (int i = 0; i < 8; ++i) {
        int n0 = 256 + i*16;
        f32x4 acc = f32x4{0.f,0.f,0.f,0.f};
#pragma unroll
        for (int kc = 0; kc < 4; ++kc) {
          bf16x8 bi_ = *(const bf16x8*)(&Wihbf[(size_t)(n0+lm)*128 + kc*32 + lq*8]);
          acc = __builtin_amdgcn_mfma_f32_16x16x32_bf16(ax[kc], bi_, acc, 0,0,0);
        }
#pragma unroll
        for (int reg = 0; reg < 4; ++reg)
          G_in[(lq*4+reg)*128 + i*16 + lm] = acc[reg];
      }
    } else {
#pragma unroll
      for (int i = 0; i < 8; ++i) {
        int n0 = 256 + i*16;
        f32x4 acc = f32x4{0.f,0.f,0.f,0.f};
#pragma unroll
        for (int kc = 0; kc < 4; ++kc) {
          bf16x8 bh_ = *(const bf16x8*)(&Whhbf[(size_t)(n0+lm)*128 + kc*32 + lq*8]);
          acc = __builtin_amdgcn_mfma_f32_16x16x32_bf16(ah[kc], bh_, acc, 0,0,0);
        }
#pragma unroll
        for (int reg = 0; reg < 4; ++reg)
          G_hn[(lq*4+reg)*128 + i*16 + lm] = acc[reg];
      }
    }
  }
  __syncthreads();

  // ---- phase C: elementwise GRU + LN -> Fhn ----
  {
    int r = t >> 4, dseg = t & 15, ds8 = dseg*8;
    float hp[8];
    float s1 = 0.f, s2 = 0.f;
#pragma unroll
    for (int j = 0; j < 8; ++j) {
      int d = ds8 + j;
      float rg = G_rz[r*256 + d] + bih[d] + bhh[d];
      float zg = G_rz[r*256 + 128 + d] + bih[128+d] + bhh[128+d];
      float ing = G_in[r*128 + d] + bih[256+d];
      float hng = G_hn[r*128 + d] + bhh[256+d];
      float rv = 1.f/(1.f + expf(-rg));
      float zv = 1.f/(1.f + expf(-zg));
      float nv = tanhf(ing + rv*hng);
      float h0 = hs_[r*128 + d];
      float h = (1.f - zv)*nv + zv*h0;
      hp[j] = h;
      s1 += h; s2 += h*h;
    }
#pragma unroll
    for (int m = 8; m >= 1; m >>= 1) {
      s1 += __shfl_xor(s1, m, 16);
      s2 += __shfl_xor(s2, m, 16);
    }
    float mean = s1*(1.f/128.f);
    float var = s2*(1.f/128.f) - mean*mean;
    float rstd = rsqrtf(var + 1e-5f);
    float hv[8];
#pragma unroll
    for (int j = 0; j < 8; ++j) {
      int d = ds8 + j;
      hv[j] = (hp[j] - mean)*rstd*mlp_g[d] + mlp_b[d];
    }
    int fa = ((dseg >> 2)*64 + (dseg & 3)*16 + r)*8;
    *(uint4*)&Fhn[fa] = make_uint4(pack2(hv[0],hv[1]), pack2(hv[2],hv[3]),
                                   pack2(hv[4],hv[5]), pack2(hv[6],hv[7]));
  }
  __syncthreads();

  // ---- phase D: MLP1 + gelu -> Ft1 ----
  {
    bf16x8 af[4];
#pragma unroll
    for (int kc = 0; kc < 4; ++kc)
      af[kc] = *(const bf16x8*)(&Fhn[(kc*64 + ln)*8]);
#pragma unroll
    for (int i = 0; i < 8; ++i) {
      int n0 = (w*8 + i)*16;
      f32x4 acc = f32x4{0.f,0.f,0.f,0.f};
#pragma unroll
      for (int kc = 0; kc < 4; ++kc) {
        bf16x8 bw = *(const bf16x8*)(&W1bf[(size_t)(n0+lm)*128 + kc*32 + lq*8]);
        acc = __builtin_amdgcn_mfma_f32_16x16x32_bf16(af[kc], bw, acc, 0,0,0);
      }
      int kdim = n0 + lm;
      float bb = b1[kdim];
      int kc2 = kdim >> 5;
      int sub = (kdim >> 3) & 3;
      int jj = kdim & 7;
#pragma unroll
      for (int reg = 0; reg < 4; ++reg) {
        float v = acc[reg] + bb;
        float gel = 0.5f*v*(1.f + erff(v*0.70710678118654752f));
        Ft1[(kc2*64 + sub*16 + lq*4 + reg)*8 + jj] = f2bf(gel);
      }
    }
  }
  __syncthreads();

  // ---- phase E: MLP2 -> slots ----
  {
#pragma unroll
    for (int i = 0; i < 2; ++i) {
      int n0 = w*32 + i*16;
      f32x4 acc = f32x4{0.f,0.f,0.f,0.f};
#pragma unroll
      for (int kc = 0; kc < 16; ++kc) {
        bf16x8 af = *(const bf16x8*)(&Ft1[(kc*64 + ln)*8]);
        bf16x8 bw = *(const bf16x8*)(&Wm2bf[(size_t)(n0+lm)*512 + kc*32 + lq*8]);
        acc = __builtin_amdgcn_mfma_f32_16x16x32_bf16(af, bw, acc, 0,0,0);
      }
      int n = n0 + lm;
      float bb = b2[n];
#pragma unroll
      for (int reg = 0; reg < 4; ++reg) {
        int row = lq*4 + reg;
        float o = acc[reg] + bb;
        slots[(size_t)(R0 + row)*128 + n] = o;
        os_[row*128 + n] = o;
        if (last) outObj[(size_t)(R0 + row)*128 + n] = o;
      }
    }
  }

  if (last) return;

  __syncthreads();
  // ---- phase F1: LN(slots) -> Fsn ----
  {
    int r = t >> 4, dseg = t & 15, ds8 = dseg*8;
    float ov[8];
    float s1 = 0.f, s2 = 0.f;
#pragma unroll
    for (int j = 0; j < 8; ++j) {
      float o = os_[r*128 + ds8 + j];
      ov[j] = o; s1 += o; s2 += o*o;
    }
#pragma unroll
    for (int m = 8; m >= 1; m >>= 1) {
      s1 += __shfl_xor(s1, m, 16);
      s2 += __shfl_xor(s2, m, 16);
    }
    float mean = s1*(1.f/128.f);
    float var = s2*(1.f/128.f) - mean*mean;
    float rstd = rsqrtf(var + 1e-5f);
    float sv[8];
#pragma unroll
    for (int j = 0; j < 8; ++j) {
      int d = ds8 + j;
      sv[j] = (ov[j] - mean)*rstd*ln_s_g[d] + ln_s_b[d];
    }
    int fa = ((dseg >> 2)*64 + (dseg & 3)*16 + r)*8;
    *(uint4*)&Fsn[fa] = make_uint4(pack2(sv[0],sv[1]), pack2(sv[2],sv[3]),
                                   pack2(sv[4],sv[5]), pack2(sv[6],sv[7]));
  }
  __syncthreads();

  // ---- phase F2: q + qkb ----
  {
    bf16x8 af[4];
#pragma unroll
    for (int kc = 0; kc < 4; ++kc)
      af[kc] = *(const bf16x8*)(&Fsn[(kc*64 + ln)*8]);
    float pr[4] = {0.f, 0.f, 0.f, 0.f};
#pragma unroll
    for (int i = 0; i < 2; ++i) {
      int n0 = w*32 + i*16;
      f32x4 acc = f32x4{0.f,0.f,0.f,0.f};
#pragma unroll
      for (int kc = 0; kc < 4; ++kc) {
        bf16x8 bw = *(const bf16x8*)(&Wqbf[(size_t)(n0+lm)*128 + kc*32 + lq*8]);
        acc = __builtin_amdgcn_mfma_f32_16x16x32_bf16(af[kc], bw, acc, 0,0,0);
      }
      int n = n0 + lm;
      float bk_ = biasArr[n];
#pragma unroll
      for (int reg = 0; reg < 4; ++reg) {
        int row = lq*4 + reg;
        qg[(size_t)(R0 + row)*128 + n] = acc[reg];
        pr[reg] += acc[reg]*bk_;
      }
    }
#pragma unroll
    for (int reg = 0; reg < 4; ++reg) {
#pragma unroll
      for (int m = 8; m >= 1; m >>= 1) pr[reg] += __shfl_xor(pr[reg], m, 16);
    }
    if (lm == 0) {
#pragma unroll
      for (int reg = 0; reg < 4; ++reg)
        atomicAdd(&qkbL[lq*4 + reg], pr[reg]);
    }
  }
  __syncthreads();
  if (t < 16) {
    qkb[R0 + t] = qkbL[t];
    SsumW[R0 + t] = 0.f;
  }
}

extern "C" void kernel_launch(void* const* d_in, const int* in_sizes, int n_in,
                              void* d_out, int out_size, void* d_ws, size_t ws_size,
                              hipStream_t stream) {
  const float* tokens = (const float*)d_in[0];
  const float* pslots = (const float*)d_in[1];
  const float* pmasks = (const float*)d_in[2];
  const float* eps    = (const float*)d_in[3];
  const float* ln_in_g= (const float*)d_in[4];
  const float* ln_in_b= (const float*)d_in[5];
  const float* ln_s_g = (const float*)d_in[6];
  const float* ln_s_b = (const float*)d_in[7];
  const float* Wq     = (const float*)d_in[8];
  const float* Wk     = (const float*)d_in[9];
  const float* Wv     = (const float*)d_in[10];
  const float* Wih    = (const float*)d_in[11];
  const float* Whh    = (const float*)d_in[12];
  const float* bih    = (const float*)d_in[13];
  const float* bhh    = (const float*)d_in[14];
  const float* mlp_g  = (const float*)d_in[15];
  const float* mlp_b  = (const float*)d_in[16];
  const float* W1     = (const float*)d_in[17];
  const float* b1     = (const float*)d_in[18];
  const float* W2     = (const float*)d_in[19];
  const float* b2     = (const float*)d_in[20];
  float* ws  = (float*)d_ws;
  float* out = (float*)d_out;
  unsigned short* wkvbf = (unsigned short*)(ws + OFF_WKVBF);
  unsigned short* wqbf  = (unsigned short*)(ws + OFF_WQBF);
  unsigned short* wihbf = (unsigned short*)(ws + OFF_WIHBF);
  unsigned short* whhbf = (unsigned short*)(ws + OFF_WHHBF);
  unsigned short* w1bf  = (unsigned short*)(ws + OFF_W1BF);
  unsigned short* wm2bf = (unsigned short*)(ws + OFF_WM2BF);
  unsigned short* kb    = (unsigned short*)(ws + OFF_KB);
  unsigned short* vt    = (unsigned short*)(ws + OFF_VT);

  prep_all_k<<<1088, 256, 0, stream>>>(Wk, Wv, ln_in_g, ln_in_b,
                                       Wq, Wih, Whh, W1, W2, pmasks,
                                       wkvbf, ws + OFF_GSUM, ws + OFF_BIAS,
                                       wqbf, wihbf, whhbf, w1bf, wm2bf,
                                       ws + OFF_DENOM);
  gemm_kv_k<<<512, 256, 0, stream>>>(tokens, wkvbf, ws + OFF_GSUM,
                                     kb, vt, ws + OFF_VAR);
  slots_init_q_k<<<8, 256, 0, stream>>>(pslots, eps, ln_s_g, ln_s_b,
                                        wqbf, ws + OFF_BIAS,
                                        ws + OFF_SLOTS, ws + OFF_Q,
                                        ws + OFF_QKB, ws + OFF_SSUM);
  for (int it = 0; it < 3; ++it) {
    int last = (it == 2);
    attn_fused_k<<<256, 128, 0, stream>>>(kb, vt, ws + OFF_Q, ws + OFF_QKB,
                                          ws + OFF_VAR, ws + OFF_DENOM, pmasks,
                                          ws + OFF_UPART, ws + OFF_SSUM,
                                          out + 16384, last);
    gru_mlp_q_k<<<8, 256, 0, stream>>>(ws + OFF_UPART, ws + OFF_SSUM,
                                       ws + OFF_BIAS, wihbf, whhbf, bih, bhh,
                                       mlp_g, mlp_b, w1bf, b1, wm2bf, b2,
                                       ln_s_g, ln_s_b, wqbf,
                                       ws + OFF_SLOTS, ws + OFF_Q, ws + OFF_QKB,
                                       ws + OFF_SSUM, out, last);
  }
}

// Round 7
// 332.318 us; speedup vs baseline: 1.1969x; 1.1329x over previous
//
#include <hip/hip_runtime.h>
#include <hip/hip_bf16.h>
#include <math.h>

#define SCALE_ 0.08838834764831843f

typedef __attribute__((ext_vector_type(8))) short bf16x8;
typedef __attribute__((ext_vector_type(4))) float f32x4;

// ---- workspace layout (float offsets), total ~5.53M floats = 22 MB ----
static const size_t OFF_VAR   = 0;        // 32768
static const size_t OFF_DENOM = 32768;    // 64
static const size_t OFF_GSUM  = 32832;    // 256 (unused now)
static const size_t OFF_BIAS  = 33088;    // 256
static const size_t OFF_QKB   = 33344;    // 128
static const size_t OFF_SSUM  = 33472;    // 128
static const size_t OFF_SLOTS = 33600;    // 16384
static const size_t OFF_Q     = 49984;    // 16384
static const size_t OFF_WQBF  = 66368;    // 8192 fl Wq[128][128] bf16
static const size_t OFF_WIHBF = 74560;    // 24576 fl Wih[384][128] bf16
static const size_t OFF_WHHBF = 99136;    // 24576 fl Whh[384][128] bf16
static const size_t OFF_W1BF  = 123712;   // 32768 fl W1[512][128] bf16
static const size_t OFF_WM2BF = 156480;   // 32768 fl W2[128][512] bf16
static const size_t OFF_WKVBF = 189248;   // 98304 fl (196608 bf16) [256][768] SWIZZLED, mean-folded
static const size_t OFF_UPART = 287552;   // 524288 fl [8][32][16][128]
static const size_t OFF_KB    = 1336128;  // 2097152 fl (4194304 bf16) [b][n][128]
static const size_t OFF_VT    = 3433280;  // 2097152 fl (4194304 bf16) [b][128][4096]

__device__ __forceinline__ float wred64(float v) {
#pragma unroll
  for (int off = 32; off > 0; off >>= 1) v += __shfl_xor(v, off, 64);
  return v;
}

__device__ __forceinline__ unsigned short f2bf(float f) {
  unsigned u = __float_as_uint(f);
  unsigned r = (u + 0x7fffu + ((u >> 16) & 1u)) >> 16;
  return (unsigned short)r;
}

// packed fp32x2 -> bf16x2 via v_cvt_pk_bf16_f32 (RNE); a in low 16, b in high
__device__ __forceinline__ unsigned pack2(float a, float b) {
  float2 f; f.x = a; f.y = b;
  __hip_bfloat162 h = __float22bfloat162_rn(f);
  unsigned r;
  __builtin_memcpy(&r, &h, 4);
  return r;
}

// ---- 1. merged prep: wkv (swizzled bf16, mean-folded), bias, bf16 weights, denom
__global__ __launch_bounds__(256) void prep_all_k(
    const float* __restrict__ Wk, const float* __restrict__ Wv,
    const float* __restrict__ g, const float* __restrict__ bb,
    const float* __restrict__ Wq, const float* __restrict__ Wih,
    const float* __restrict__ Whh, const float* __restrict__ W1,
    const float* __restrict__ W2, const float* __restrict__ pm,
    unsigned short* __restrict__ wkv, float* __restrict__ biasArr,
    unsigned short* __restrict__ Wqbf, unsigned short* __restrict__ Wihbf,
    unsigned short* __restrict__ Whhbf, unsigned short* __restrict__ W1bf,
    unsigned short* __restrict__ Wm2bf, float* __restrict__ denomArr)
{
  __shared__ float red4[4];
  int bi = blockIdx.x, t = threadIdx.x;
  if (bi < 64) {
    // fold LN gain into Wk/Wv AND fold mean-correction: W' = g*W - gsum/768
    int j = bi*4 + (t >> 6), lane = t & 63;
    const float* w = (j < 128) ? (Wk + (size_t)j*768) : (Wv + (size_t)(j-128)*768);
    float gs = 0.f, bs = 0.f;
    float st[12];
    int key = j & 7;
#pragma unroll
    for (int s = 0; s < 12; ++s) {
      int dd = lane + s*64;
      float wv = w[dd], gv = g[dd];
      st[s] = wv*gv;
      gs += st[s]; bs += bb[dd]*wv;
    }
    gs = wred64(gs); bs = wred64(bs);
    float corr = gs*(1.f/768.f);
#pragma unroll
    for (int s = 0; s < 12; ++s) {
      int dd = lane + s*64;
      int sw = (dd & ~63) | (((((dd >> 3) & 7) ^ key)) << 3) | (dd & 7);
      wkv[(size_t)j*768 + sw] = f2bf(st[s] - corr);
    }
    if (lane == 0) biasArr[j] = bs;
  } else if (bi < 128) {
    int idx = (bi-64)*256 + t;  Wqbf[idx]  = f2bf(Wq[idx]);
  } else if (bi < 320) {
    int idx = (bi-128)*256 + t; Wihbf[idx] = f2bf(Wih[idx]);
  } else if (bi < 512) {
    int idx = (bi-320)*256 + t; Whhbf[idx] = f2bf(Whh[idx]);
  } else if (bi < 768) {
    int idx = (bi-512)*256 + t; W1bf[idx]  = f2bf(W1[idx]);
  } else if (bi < 1024) {
    int idx = (bi-768)*256 + t; Wm2bf[idx] = f2bf(W2[idx]);
  } else {
    int bk = bi - 1024;
    float s = 0.f;
#pragma unroll
    for (int k = 0; k < 16; ++k) s += pm[bk*4096 + t + k*256];
    s = wred64(s);
    if ((t & 63) == 0) red4[t >> 6] = s;
    __syncthreads();
    if (t == 0) denomArr[bk] = (red4[0]+red4[1]+red4[2]+red4[3])*(1.f/4096.f);
  }
}

// ---- 2. MFMA GEMM (r4 structure): tokens[32768,768] -> Kb/VT bf16 (+ var) ----
// grid 512: block = 64 rows x 256 cols. Swizzled LDS (0 conflicts measured).
__global__ __launch_bounds__(256) void gemm_kv_k(
    const float* __restrict__ tokens, const unsigned short* __restrict__ wkv,
    unsigned short* __restrict__ Kb, unsigned short* __restrict__ VT,
    float* __restrict__ varArr)
{
  __shared__ unsigned short As[64*64];   // swizzled
  __shared__ unsigned short Bs[256*64];  // swizzled via pre-swizzled wkv
  int r0 = blockIdx.x*64;
  int t = threadIdx.x;
  int w = t >> 6, lane = t & 63;
  int lm = lane & 15, lq = lane >> 4;
  int g16 = t >> 4, seg = t & 15;
  int m0 = (w >> 1)*32, n0 = (w & 1)*128;

  f32x4 acc[2][8];
#pragma unroll
  for (int a = 0; a < 2; ++a)
#pragma unroll
    for (int c = 0; c < 8; ++c) acc[a][c] = f32x4{0.f, 0.f, 0.f, 0.f};
  float s1[4] = {0.f,0.f,0.f,0.f}, s2[4] = {0.f,0.f,0.f,0.f};

  for (int k0 = 0; k0 < 768; k0 += 64) {
    __syncthreads();
#pragma unroll
    for (int s = 0; s < 8; ++s) {
      int row = w*64 + s*8;
      __builtin_amdgcn_global_load_lds(
        (const __attribute__((address_space(1))) void*)
          (wkv + (size_t)(row + (lane >> 3))*768 + k0 + (lane & 7)*8),
        (__attribute__((address_space(3))) void*)(&Bs[row*64]), 16, 0, 0);
    }
#pragma unroll
    for (int p = 0; p < 4; ++p) {
      int row = p*16 + g16;
      float4 x = *(const float4*)(tokens + (size_t)(r0 + row)*768 + k0 + seg*4);
      s1[p] += x.x + x.y + x.z + x.w;
      s2[p] += x.x*x.x + x.y*x.y + x.z*x.z + x.w*x.w;
      int off = row*64 + (((seg >> 1) ^ (row & 7)) << 3) + (seg & 1)*4;
      *(uint2*)(&As[off]) = make_uint2(pack2(x.x, x.y), pack2(x.z, x.w));
    }
    __syncthreads();
#pragma unroll
    for (int kk8 = 0; kk8 < 8; kk8 += 4) {
      bf16x8 af[2], bfr[8];
#pragma unroll
      for (int mt = 0; mt < 2; ++mt) {
        int row = m0 + mt*16 + lm;
        af[mt] = *(const bf16x8*)(&As[row*64 + (((kk8 + lq) ^ (row & 7)) << 3)]);
      }
#pragma unroll
      for (int nt = 0; nt < 8; ++nt) {
        int row = n0 + nt*16 + lm;
        bfr[nt] = *(const bf16x8*)(&Bs[row*64 + (((kk8 + lq) ^ (row & 7)) << 3)]);
      }
#pragma unroll
      for (int mt = 0; mt < 2; ++mt)
#pragma unroll
        for (int nt = 0; nt < 8; ++nt)
          acc[mt][nt] = __builtin_amdgcn_mfma_f32_16x16x32_bf16(
              af[mt], bfr[nt], acc[mt][nt], 0, 0, 0);
    }
  }
#pragma unroll
  for (int p = 0; p < 4; ++p) {
#pragma unroll
    for (int m = 8; m >= 1; m >>= 1) {
      s1[p] += __shfl_xor(s1[p], m, 16);
      s2[p] += __shfl_xor(s2[p], m, 16);
    }
  }
  if (seg == 0) {
#pragma unroll
    for (int p = 0; p < 4; ++p) {
      int row = p*16 + g16;
      float m = s1[p]*(1.f/768.f);
      varArr[r0 + row] = s2[p]*(1.f/768.f) - m*m;
    }
  }
  // epilogue: no mean correction needed (folded into weights)
  if ((w & 1) == 0) {
    // K: cols 0..127 -> Kb[tok][col]
#pragma unroll
    for (int nt = 0; nt < 8; ++nt) {
      int col = nt*16 + lm;
#pragma unroll
      for (int mt = 0; mt < 2; ++mt) {
#pragma unroll
        for (int reg = 0; reg < 4; ++reg) {
          int tok = r0 + m0 + mt*16 + lq*4 + reg;
          Kb[(size_t)tok*128 + col] = f2bf(acc[mt][nt][reg]);
        }
      }
    }
  } else {
    // V: cols 128..255 -> VT[b][d][n], 4 consecutive n per lane
#pragma unroll
    for (int nt = 0; nt < 8; ++nt) {
      int d = nt*16 + lm;
#pragma unroll
      for (int mt = 0; mt < 2; ++mt) {
        int tok0 = r0 + m0 + mt*16 + lq*4;
        int b = tok0 >> 12;
        int n = tok0 & 4095;
        uint2 v = make_uint2(pack2(acc[mt][nt][0], acc[mt][nt][1]),
                             pack2(acc[mt][nt][2], acc[mt][nt][3]));
        *(uint2*)&VT[((size_t)(b*128 + d))*4096 + n] = v;
      }
    }
  }
}

// ---- 3. slots init + LN + q (iter 0), MFMA; zeroes Ssum ----
__global__ __launch_bounds__(256, 1) void slots_init_q_k(
    const float* __restrict__ ps, const float* __restrict__ eps,
    const float* __restrict__ g_s, const float* __restrict__ b_s,
    const unsigned short* __restrict__ Wqbf, const float* __restrict__ biasArr,
    float* __restrict__ slots, float* __restrict__ qg, float* __restrict__ qkb,
    float* __restrict__ Ssum)
{
  __shared__ unsigned short Fsn[2048];
  __shared__ float qkbL[16];
  int R0 = blockIdx.x*16;
  int t = threadIdx.x;
  int w = t >> 6, ln = t & 63, lm = ln & 15, lq = ln >> 4;
  if (t < 16) qkbL[t] = 0.f;
  {
    int r = t >> 4, dseg = t & 15, ds8 = dseg*8;
    int row = R0 + r, bk = row >> 1;
    float xv[8]; float s1 = 0.f, s2 = 0.f;
#pragma unroll
    for (int j = 0; j < 8; ++j) {
      int d = ds8 + j;
      float x = ps[bk*128 + d] + 0.01f*eps[row*128 + d];
      slots[row*128 + d] = x;
      xv[j] = x; s1 += x; s2 += x*x;
    }
#pragma unroll
    for (int m = 8; m >= 1; m >>= 1) {
      s1 += __shfl_xor(s1, m, 16);
      s2 += __shfl_xor(s2, m, 16);
    }
    float mean = s1*(1.f/128.f);
    float var = s2*(1.f/128.f) - mean*mean;
    float rstd = rsqrtf(var + 1e-5f);
    float sv[8];
#pragma unroll
    for (int j = 0; j < 8; ++j) {
      int d = ds8 + j;
      sv[j] = (xv[j] - mean)*rstd*g_s[d] + b_s[d];
    }
    int fa = ((dseg >> 2)*64 + (dseg & 3)*16 + r)*8;
    *(uint4*)&Fsn[fa] = make_uint4(pack2(sv[0],sv[1]), pack2(sv[2],sv[3]),
                                   pack2(sv[4],sv[5]), pack2(sv[6],sv[7]));
  }
  __syncthreads();
  {
    bf16x8 af[4];
#pragma unroll
    for (int kc = 0; kc < 4; ++kc)
      af[kc] = *(const bf16x8*)(&Fsn[(kc*64 + ln)*8]);
    float pr[4] = {0.f, 0.f, 0.f, 0.f};
#pragma unroll
    for (int i = 0; i < 2; ++i) {
      int n0 = w*32 + i*16;
      f32x4 acc = f32x4{0.f,0.f,0.f,0.f};
#pragma unroll
      for (int kc = 0; kc < 4; ++kc) {
        bf16x8 bw = *(const bf16x8*)(&Wqbf[(size_t)(n0+lm)*128 + kc*32 + lq*8]);
        acc = __builtin_amdgcn_mfma_f32_16x16x32_bf16(af[kc], bw, acc, 0,0,0);
      }
      int n = n0 + lm;
      float bk_ = biasArr[n];
#pragma unroll
      for (int reg = 0; reg < 4; ++reg) {
        int row = lq*4 + reg;
        qg[(size_t)(R0 + row)*128 + n] = acc[reg];
        pr[reg] += acc[reg]*bk_;
      }
    }
#pragma unroll
    for (int reg = 0; reg < 4; ++reg) {
#pragma unroll
      for (int m = 8; m >= 1; m >>= 1) pr[reg] += __shfl_xor(pr[reg], m, 16);
    }
    if (lm == 0) {
#pragma unroll
      for (int reg = 0; reg < 4; ++reg)
        atomicAdd(&qkbL[lq*4 + reg], pr[reg]);
    }
  }
  __syncthreads();
  if (t < 16) { qkb[R0 + t] = qkbL[t]; Ssum[R0 + t] = 0.f; }
}

// ---- 4. MFMA fused attention; block-level U reduction (1 partial/block) ----
__global__ __launch_bounds__(128) void attn_fused_k(
    const unsigned short* __restrict__ Kb, const unsigned short* __restrict__ VT,
    const float* __restrict__ qg, const float* __restrict__ qkb,
    const float* __restrict__ varArr, const float* __restrict__ denomArr,
    const float* __restrict__ pm,
    float* __restrict__ Upart, float* __restrict__ Ssum,
    float* __restrict__ outG, int last)
{
  __shared__ unsigned short Pl[2][16*68];
  __shared__ float Upw[2][2048];
  int bi = blockIdx.x;
  int b = bi >> 5, nch = bi & 31;
  int t = threadIdx.x;
  int wv = t >> 6, ln = t & 63;
  int lm = ln & 15, lq = ln >> 4;
  int ntok0 = nch*128 + wv*64;
  unsigned short* pl = &Pl[wv][0];

  bf16x8 qf[4];
#pragma unroll
  for (int kc = 0; kc < 4; ++kc) {
    const float* qp = qg + (size_t)(b*16 + lm)*128 + kc*32 + lq*8;
    float4 q0 = *(const float4*)qp;
    float4 q1 = *(const float4*)(qp + 4);
    uint4 tmp = make_uint4(pack2(q0.x,q0.y), pack2(q0.z,q0.w),
                           pack2(q1.x,q1.y), pack2(q1.z,q1.w));
    qf[kc] = *(bf16x8*)&tmp;
  }
  float qkbv[4];
#pragma unroll
  for (int reg = 0; reg < 4; ++reg) qkbv[reg] = qkb[b*16 + lq*4 + reg];
  float den0 = denomArr[b*8 + lq*2];
  float den1 = denomArr[b*8 + lq*2 + 1];
  bool g0 = den0 > 1e-6f, g1 = den1 > 1e-6f;
  float inv0 = 1.f/(den0 + 1e-6f), inv1 = 1.f/(den1 + 1e-6f);

  f32x4 Uacc[8];
#pragma unroll
  for (int dt = 0; dt < 8; ++dt) Uacc[dt] = f32x4{0.f,0.f,0.f,0.f};
  float sAcc[4] = {0.f, 0.f, 0.f, 0.f};

#pragma unroll
  for (int half = 0; half < 2; ++half) {
    int tk0 = ntok0 + half*32;
#pragma unroll
    for (int ti = 0; ti < 2; ++ti) {
      int n0 = tk0 + ti*16;
      int n = n0 + lm;
      f32x4 dacc = f32x4{0.f,0.f,0.f,0.f};
      const unsigned short* kp = Kb + ((size_t)(b*4096 + n))*128 + lq*8;
#pragma unroll
      for (int kc = 0; kc < 4; ++kc) {
        bf16x8 kf = *(const bf16x8*)(kp + kc*32);
        dacc = __builtin_amdgcn_mfma_f32_16x16x32_bf16(qf[kc], kf, dacc, 0,0,0);
      }
      float vv = varArr[b*4096 + n];
      float pm0 = pm[((size_t)(b*8 + lq*2))*4096 + n];
      float pm1 = pm[((size_t)(b*8 + lq*2 + 1))*4096 + n];
      float c0 = g0 ? pm0*inv0 : 1.f;
      float c1 = g1 ? pm1*inv1 : 1.f;
      float al0 = c0*rsqrtf(c0*c0*vv + 1e-5f);
      float al1 = c1*rsqrtf(c1*c1*vv + 1e-5f);
      float dd0 = SCALE_*(al0*dacc[0] + qkbv[0]);
      float dd1 = SCALE_*(al0*dacc[1] + qkbv[1]);
      float mx0 = fmaxf(dd0, dd1);
      float e0 = expf(dd0 - mx0), e1 = expf(dd1 - mx0);
      float is0 = 1.f/(e0 + e1);
      float o0 = e0*is0 + 1e-8f, o1 = e1*is0 + 1e-8f;
      float dd2 = SCALE_*(al1*dacc[2] + qkbv[2]);
      float dd3 = SCALE_*(al1*dacc[3] + qkbv[3]);
      float mx1 = fmaxf(dd2, dd3);
      float e2 = expf(dd2 - mx1), e3 = expf(dd3 - mx1);
      float is1 = 1.f/(e2 + e3);
      float o2 = e2*is1 + 1e-8f, o3 = e3*is1 + 1e-8f;
      sAcc[0] += o0; sAcc[1] += o1; sAcc[2] += o2; sAcc[3] += o3;
      if (last) {
        size_t ob = ((size_t)(b*16 + lq*4))*4096 + n;
        outG[ob]          = o0*pm0;
        outG[ob + 4096]   = o1*pm0;
        outG[ob + 8192]   = o2*pm1;
        outG[ob + 12288]  = o3*pm1;
      }
      int pc = half*32 + ti*16 + lm;
      pl[(lq*4 + 0)*68 + pc] = f2bf(o0*al0);
      pl[(lq*4 + 1)*68 + pc] = f2bf(o1*al0);
      pl[(lq*4 + 2)*68 + pc] = f2bf(o2*al1);
      pl[(lq*4 + 3)*68 + pc] = f2bf(o3*al1);
    }
    bf16x8 pf = *(const bf16x8*)&pl[lm*68 + half*32 + lq*8];
    const unsigned short* vp = VT + ((size_t)(b*128 + lm))*4096 + tk0 + lq*8;
#pragma unroll
    for (int dt = 0; dt < 8; ++dt) {
      bf16x8 vf = *(const bf16x8*)(vp + (size_t)(dt*16)*4096);
      Uacc[dt] = __builtin_amdgcn_mfma_f32_16x16x32_bf16(pf, vf, Uacc[dt], 0,0,0);
    }
  }

#pragma unroll
  for (int reg = 0; reg < 4; ++reg) {
    float r = sAcc[reg];
    r += __shfl_xor(r, 1, 64); r += __shfl_xor(r, 2, 64);
    r += __shfl_xor(r, 4, 64); r += __shfl_xor(r, 8, 64);
    if (lm == 0) atomicAdd(&Ssum[b*16 + lq*4 + reg], r);
  }
  // block-level U reduction: both waves -> LDS, then one coalesced partial
  float* uw = &Upw[wv][0];
#pragma unroll
  for (int dt = 0; dt < 8; ++dt)
#pragma unroll
    for (int reg = 0; reg < 4; ++reg)
      uw[(lq*4 + reg)*128 + dt*16 + lm] = Uacc[dt][reg];
  __syncthreads();
  float* up = Upart + (size_t)(b*32 + nch)*2048;
#pragma unroll
  for (int i = 0; i < 4; ++i) {
    int idx = t*16 + i*4;
    float4 a = *(const float4*)&Upw[0][idx];
    float4 c = *(const float4*)&Upw[1][idx];
    float4 o; o.x = a.x + c.x; o.y = a.y + c.y; o.z = a.z + c.z; o.w = a.w + c.w;
    *(float4*)&up[idx] = o;
  }
}

// ---- 5. GRU + MLP + next-iter q (MFMA); sums 32-chunk Upart ----
__global__ __launch_bounds__(256, 1) void gru_mlp_q_k(
    const float* __restrict__ Upart, const float* __restrict__ Ssum,
    const float* __restrict__ biasArr,
    const unsigned short* __restrict__ Wihbf, const unsigned short* __restrict__ Whhbf,
    const float* __restrict__ bih, const float* __restrict__ bhh,
    const float* __restrict__ mlp_g, const float* __restrict__ mlp_b,
    const unsigned short* __restrict__ W1bf, const float* __restrict__ b1,
    const unsigned short* __restrict__ Wm2bf, const float* __restrict__ b2,
    const float* __restrict__ ln_s_g, const float* __restrict__ ln_s_b,
    const unsigned short* __restrict__ Wqbf,
    float* __restrict__ slots, float* __restrict__ qg, float* __restrict__ qkb,
    float* __restrict__ SsumW, float* __restrict__ outObj, int last)
{
  __shared__ unsigned short FXx[2048], FXh[2048], Fhn[2048], Fsn[2048];
  __shared__ unsigned short Ft1[8192];
  __shared__ float G_rz[16*256];
  __shared__ float G_in[16*128];
  __shared__ float G_hn[16*128];
  __shared__ float hs_[16*128];
  __shared__ float os_[16*128];
  __shared__ float qkbL[16];

  int R0 = blockIdx.x*16;
  int t = threadIdx.x;
  int w = t >> 6, ln = t & 63;
  int lm = ln & 15, lq = ln >> 4;

  // ---- phase A: sum 32 partials, build frags ----
  {
    int r = t >> 4, dseg = t & 15, ds8 = dseg*8;
    int R = R0 + r;
    float ua[8];
#pragma unroll
    for (int j = 0; j < 8; ++j) ua[j] = 0.f;
    const float* up = Upart + (size_t)blockIdx.x*65536 + r*128 + ds8;
#pragma unroll 8
    for (int ch = 0; ch < 32; ++ch) {
      float4 u0 = *(const float4*)(up + (size_t)ch*2048);
      float4 u1 = *(const float4*)(up + (size_t)ch*2048 + 4);
      ua[0]+=u0.x; ua[1]+=u0.y; ua[2]+=u0.z; ua[3]+=u0.w;
      ua[4]+=u1.x; ua[5]+=u1.y; ua[6]+=u1.z; ua[7]+=u1.w;
    }
    float Sv = 1.f/Ssum[R];
    float4 bv0 = *(const float4*)(biasArr + 128 + ds8);
    float4 bv1 = *(const float4*)(biasArr + 132 + ds8);
    float xv[8];
    xv[0]=ua[0]*Sv+bv0.x; xv[1]=ua[1]*Sv+bv0.y; xv[2]=ua[2]*Sv+bv0.z; xv[3]=ua[3]*Sv+bv0.w;
    xv[4]=ua[4]*Sv+bv1.x; xv[5]=ua[5]*Sv+bv1.y; xv[6]=ua[6]*Sv+bv1.z; xv[7]=ua[7]*Sv+bv1.w;
    float4 h0 = *(const float4*)(slots + (size_t)R*128 + ds8);
    float4 h1 = *(const float4*)(slots + (size_t)R*128 + ds8 + 4);
    *(float4*)(hs_ + r*128 + ds8) = h0;
    *(float4*)(hs_ + r*128 + ds8 + 4) = h1;
    int fa = ((dseg >> 2)*64 + (dseg & 3)*16 + r)*8;
    *(uint4*)&FXx[fa] = make_uint4(pack2(xv[0],xv[1]), pack2(xv[2],xv[3]),
                                   pack2(xv[4],xv[5]), pack2(xv[6],xv[7]));
    *(uint4*)&FXh[fa] = make_uint4(pack2(h0.x,h0.y), pack2(h0.z,h0.w),
                                   pack2(h1.x,h1.y), pack2(h1.z,h1.w));
    if (t < 16) qkbL[t] = 0.f;
  }
  __syncthreads();

  // ---- phase B: GRU gemms ----
  {
    bf16x8 ax[4], ah[4];
#pragma unroll
    for (int kc = 0; kc < 4; ++kc) {
      ax[kc] = *(const bf16x8*)(&FXx[(kc*64 + ln)*8]);
      ah[kc] = *(const bf16x8*)(&FXh[(kc*64 + ln)*8]);
    }
    if (w < 2) {
#pragma unroll
      for (int i = 0; i < 8; ++i) {
        int n0 = (w*8 + i)*16;
        f32x4 acc = f32x4{0.f,0.f,0.f,0.f};
#pragma unroll
        for (int kc = 0; kc < 4; ++kc) {
          bf16x8 bi_ = *(const bf16x8*)(&Wihbf[(size_t)(n0+lm)*128 + kc*32 + lq*8]);
          acc = __builtin_amdgcn_mfma_f32_16x16x32_bf16(ax[kc], bi_, acc, 0,0,0);
        }
#pragma unroll
        for (int kc = 0; kc < 4; ++kc) {
          bf16x8 bh_ = *(const bf16x8*)(&Whhbf[(size_t)(n0+lm)*128 + kc*32 + lq*8]);
          acc = __builtin_amdgcn_mfma_f32_16x16x32_bf16(ah[kc], bh_, acc, 0,0,0);
        }
#pragma unroll
        for (int reg = 0; reg < 4; ++reg)
          G_rz[(lq*4+reg)*256 + n0 + lm] = acc[reg];
      }
    } else if (w == 2) {
#pragma unroll
      for (int i = 0; i < 8; ++i) {
        int n0 = 256 + i*16;
        f32x4 acc = f32x4{0.f,0.f,0.f,0.f};
#pragma unroll
        for (int kc = 0; kc < 4; ++kc) {
          bf16x8 bi_ = *(const bf16x8*)(&Wihbf[(size_t)(n0+lm)*128 + kc*32 + lq*8]);
          acc = __builtin_amdgcn_mfma_f32_16x16x32_bf16(ax[kc], bi_, acc, 0,0,0);
        }
#pragma unroll
        for (int reg = 0; reg < 4; ++reg)
          G_in[(lq*4+reg)*128 + i*16 + lm] = acc[reg];
      }
    } else {
#pragma unroll
      for (int i = 0; i < 8; ++i) {
        int n0 = 256 + i*16;
        f32x4 acc = f32x4{0.f,0.f,0.f,0.f};
#pragma unroll
        for (int kc = 0; kc < 4; ++kc) {
          bf16x8 bh_ = *(const bf16x8*)(&Whhbf[(size_t)(n0+lm)*128 + kc*32 + lq*8]);
          acc = __builtin_amdgcn_mfma_f32_16x16x32_bf16(ah[kc], bh_, acc, 0,0,0);
        }
#pragma unroll
        for (int reg = 0; reg < 4; ++reg)
          G_hn[(lq*4+reg)*128 + i*16 + lm] = acc[reg];
      }
    }
  }
  __syncthreads();

  // ---- phase C: elementwise GRU + LN -> Fhn ----
  {
    int r = t >> 4, dseg = t & 15, ds8 = dseg*8;
    float hp[8];
    float s1 = 0.f, s2 = 0.f;
#pragma unroll
    for (int j = 0; j < 8; ++j) {
      int d = ds8 + j;
      float rg = G_rz[r*256 + d] + bih[d] + bhh[d];
      float zg = G_rz[r*256 + 128 + d] + bih[128+d] + bhh[128+d];
      float ing = G_in[r*128 + d] + bih[256+d];
      float hng = G_hn[r*128 + d] + bhh[256+d];
      float rv = 1.f/(1.f + expf(-rg));
      float zv = 1.f/(1.f + expf(-zg));
      float nv = tanhf(ing + rv*hng);
      float h0 = hs_[r*128 + d];
      float h = (1.f - zv)*nv + zv*h0;
      hp[j] = h;
      s1 += h; s2 += h*h;
    }
#pragma unroll
    for (int m = 8; m >= 1; m >>= 1) {
      s1 += __shfl_xor(s1, m, 16);
      s2 += __shfl_xor(s2, m, 16);
    }
    float mean = s1*(1.f/128.f);
    float var = s2*(1.f/128.f) - mean*mean;
    float rstd = rsqrtf(var + 1e-5f);
    float hv[8];
#pragma unroll
    for (int j = 0; j < 8; ++j) {
      int d = ds8 + j;
      hv[j] = (hp[j] - mean)*rstd*mlp_g[d] + mlp_b[d];
    }
    int fa = ((dseg >> 2)*64 + (dseg & 3)*16 + r)*8;
    *(uint4*)&Fhn[fa] = make_uint4(pack2(hv[0],hv[1]), pack2(hv[2],hv[3]),
                                   pack2(hv[4],hv[5]), pack2(hv[6],hv[7]));
  }
  __syncthreads();

  // ---- phase D: MLP1 + gelu -> Ft1 ----
  {
    bf16x8 af[4];
#pragma unroll
    for (int kc = 0; kc < 4; ++kc)
      af[kc] = *(const bf16x8*)(&Fhn[(kc*64 + ln)*8]);
#pragma unroll
    for (int i = 0; i < 8; ++i) {
      int n0 = (w*8 + i)*16;
      f32x4 acc = f32x4{0.f,0.f,0.f,0.f};
#pragma unroll
      for (int kc = 0; kc < 4; ++kc) {
        bf16x8 bw = *(const bf16x8*)(&W1bf[(size_t)(n0+lm)*128 + kc*32 + lq*8]);
        acc = __builtin_amdgcn_mfma_f32_16x16x32_bf16(af[kc], bw, acc, 0,0,0);
      }
      int kdim = n0 + lm;
      float bb = b1[kdim];
      int kc2 = kdim >> 5;
      int sub = (kdim >> 3) & 3;
      int jj = kdim & 7;
#pragma unroll
      for (int reg = 0; reg < 4; ++reg) {
        float v = acc[reg] + bb;
        float gel = 0.5f*v*(1.f + erff(v*0.70710678118654752f));
        Ft1[(kc2*64 + sub*16 + lq*4 + reg)*8 + jj] = f2bf(gel);
      }
    }
  }
  __syncthreads();

  // ---- phase E: MLP2 -> slots ----
  {
#pragma unroll
    for (int i = 0; i < 2; ++i) {
      int n0 = w*32 + i*16;
      f32x4 acc = f32x4{0.f,0.f,0.f,0.f};
#pragma unroll
      for (int kc = 0; kc < 16; ++kc) {
        bf16x8 af = *(const bf16x8*)(&Ft1[(kc*64 + ln)*8]);
        bf16x8 bw = *(const bf16x8*)(&Wm2bf[(size_t)(n0+lm)*512 + kc*32 + lq*8]);
        acc = __builtin_amdgcn_mfma_f32_16x16x32_bf16(af, bw, acc, 0,0,0);
      }
      int n = n0 + lm;
      float bb = b2[n];
#pragma unroll
      for (int reg = 0; reg < 4; ++reg) {
        int row = lq*4 + reg;
        float o = acc[reg] + bb;
        slots[(size_t)(R0 + row)*128 + n] = o;
        os_[row*128 + n] = o;
        if (last) outObj[(size_t)(R0 + row)*128 + n] = o;
      }
    }
  }

  if (last) return;

  __syncthreads();
  // ---- phase F1: LN(slots) -> Fsn ----
  {
    int r = t >> 4, dseg = t & 15, ds8 = dseg*8;
    float ov[8];
    float s1 = 0.f, s2 = 0.f;
#pragma unroll
    for (int j = 0; j < 8; ++j) {
      float o = os_[r*128 + ds8 + j];
      ov[j] = o; s1 += o; s2 += o*o;
    }
#pragma unroll
    for (int m = 8; m >= 1; m >>= 1) {
      s1 += __shfl_xor(s1, m, 16);
      s2 += __shfl_xor(s2, m, 16);
    }
    float mean = s1*(1.f/128.f);
    float var = s2*(1.f/128.f) - mean*mean;
    float rstd = rsqrtf(var + 1e-5f);
    float sv[8];
#pragma unroll
    for (int j = 0; j < 8; ++j) {
      int d = ds8 + j;
      sv[j] = (ov[j] - mean)*rstd*ln_s_g[d] + ln_s_b[d];
    }
    int fa = ((dseg >> 2)*64 + (dseg & 3)*16 + r)*8;
    *(uint4*)&Fsn[fa] = make_uint4(pack2(sv[0],sv[1]), pack2(sv[2],sv[3]),
                                   pack2(sv[4],sv[5]), pack2(sv[6],sv[7]));
  }
  __syncthreads();

  // ---- phase F2: q + qkb ----
  {
    bf16x8 af[4];
#pragma unroll
    for (int kc = 0; kc < 4; ++kc)
      af[kc] = *(const bf16x8*)(&Fsn[(kc*64 + ln)*8]);
    float pr[4] = {0.f, 0.f, 0.f, 0.f};
#pragma unroll
    for (int i = 0; i < 2; ++i) {
      int n0 = w*32 + i*16;
      f32x4 acc = f32x4{0.f,0.f,0.f,0.f};
#pragma unroll
      for (int kc = 0; kc < 4; ++kc) {
        bf16x8 bw = *(const bf16x8*)(&Wqbf[(size_t)(n0+lm)*128 + kc*32 + lq*8]);
        acc = __builtin_amdgcn_mfma_f32_16x16x32_bf16(af[kc], bw, acc, 0,0,0);
      }
      int n = n0 + lm;
      float bk_ = biasArr[n];
#pragma unroll
      for (int reg = 0; reg < 4; ++reg) {
        int row = lq*4 + reg;
        qg[(size_t)(R0 + row)*128 + n] = acc[reg];
        pr[reg] += acc[reg]*bk_;
      }
    }
#pragma unroll
    for (int reg = 0; reg < 4; ++reg) {
#pragma unroll
      for (int m = 8; m >= 1; m >>= 1) pr[reg] += __shfl_xor(pr[reg], m, 16);
    }
    if (lm == 0) {
#pragma unroll
      for (int reg = 0; reg < 4; ++reg)
        atomicAdd(&qkbL[lq*4 + reg], pr[reg]);
    }
  }
  __syncthreads();
  if (t < 16) {
    qkb[R0 + t] = qkbL[t];
    SsumW[R0 + t] = 0.f;
  }
}

extern "C" void kernel_launch(void* const* d_in, const int* in_sizes, int n_in,
                              void* d_out, int out_size, void* d_ws, size_t ws_size,
                              hipStream_t stream) {
  const float* tokens = (const float*)d_in[0];
  const float* pslots = (const float*)d_in[1];
  const float* pmasks = (const float*)d_in[2];
  const float* eps    = (const float*)d_in[3];
  const float* ln_in_g= (const float*)d_in[4];
  const float* ln_in_b= (const float*)d_in[5];
  const float* ln_s_g = (const float*)d_in[6];
  const float* ln_s_b = (const float*)d_in[7];
  const float* Wq     = (const float*)d_in[8];
  const float* Wk     = (const float*)d_in[9];
  const float* Wv     = (const float*)d_in[10];
  const float* Wih    = (const float*)d_in[11];
  const float* Whh    = (const float*)d_in[12];
  const float* bih    = (const float*)d_in[13];
  const float* bhh    = (const float*)d_in[14];
  const float* mlp_g  = (const float*)d_in[15];
  const float* mlp_b  = (const float*)d_in[16];
  const float* W1     = (const float*)d_in[17];
  const float* b1     = (const float*)d_in[18];
  const float* W2     = (const float*)d_in[19];
  const float* b2     = (const float*)d_in[20];
  float* ws  = (float*)d_ws;
  float* out = (float*)d_out;
  unsigned short* wkvbf = (unsigned short*)(ws + OFF_WKVBF);
  unsigned short* wqbf  = (unsigned short*)(ws + OFF_WQBF);
  unsigned short* wihbf = (unsigned short*)(ws + OFF_WIHBF);
  unsigned short* whhbf = (unsigned short*)(ws + OFF_WHHBF);
  unsigned short* w1bf  = (unsigned short*)(ws + OFF_W1BF);
  unsigned short* wm2bf = (unsigned short*)(ws + OFF_WM2BF);
  unsigned short* kb    = (unsigned short*)(ws + OFF_KB);
  unsigned short* vt    = (unsigned short*)(ws + OFF_VT);

  prep_all_k<<<1088, 256, 0, stream>>>(Wk, Wv, ln_in_g, ln_in_b,
                                       Wq, Wih, Whh, W1, W2, pmasks,
                                       wkvbf, ws + OFF_BIAS,
                                       wqbf, wihbf, whhbf, w1bf, wm2bf,
                                       ws + OFF_DENOM);
  gemm_kv_k<<<512, 256, 0, stream>>>(tokens, wkvbf, kb, vt, ws + OFF_VAR);
  slots_init_q_k<<<8, 256, 0, stream>>>(pslots, eps, ln_s_g, ln_s_b,
                                        wqbf, ws + OFF_BIAS,
                                        ws + OFF_SLOTS, ws + OFF_Q,
                                        ws + OFF_QKB, ws + OFF_SSUM);
  for (int it = 0; it < 3; ++it) {
    int last = (it == 2);
    attn_fused_k<<<256, 128, 0, stream>>>(kb, vt, ws + OFF_Q, ws + OFF_QKB,
                                          ws + OFF_VAR, ws + OFF_DENOM, pmasks,
                                          ws + OFF_UPART, ws + OFF_SSUM,
                                          out + 16384, last);
    gru_mlp_q_k<<<8, 256, 0, stream>>>(ws + OFF_UPART, ws + OFF_SSUM,
                                       ws + OFF_BIAS, wihbf, whhbf, bih, bhh,
                                       mlp_g, mlp_b, w1bf, b1, wm2bf, b2,
                                       ln_s_g, ln_s_b, wqbf,
                                       ws + OFF_SLOTS, ws + OFF_Q, ws + OFF_QKB,
                                       ws + OFF_SSUM, out, last);
  }
}